// Round 1
// baseline (2721.263 us; speedup 1.0000x reference)
//
#include <hip/hip_runtime.h>
#include <math.h>

#define EPS 1e-5f

// Model dims
constexpr int NB      = 16;    // batch
constexpr int L       = 1024;  // tokens (32x32 patches)
constexpr int DM      = 128;   // d_model
constexpr int DI      = 256;   // d_inner
constexpr int DS      = 64;    // d_state
constexpr int NH      = 8;     // heads
constexpr int HD      = 32;    // head dim
constexpr int DPROJ   = 648;   // 2*DI + 2*DS + NH
constexpr int CDIM    = 384;   // DI + 2*DS

__device__ __forceinline__ float silu_f(float x){ return x / (1.f + expf(-x)); }

// ---------------- patch embed + pos layernorm ----------------
// grid 2048 (8 tokens/block), 128 threads (one per output channel)
__global__ __launch_bounds__(128) void k_patch(const float* __restrict__ x,
    const float* __restrict__ pw, const float* __restrict__ pb,
    const float* __restrict__ g, const float* __restrict__ be,
    float* __restrict__ tok){
  __shared__ float sp[8][768];
  __shared__ float red[2][8][2];
  const int blk = blockIdx.x;
  const int b  = blk >> 7;
  const int tg = (blk & 127) << 3;
  const int tid = threadIdx.x;
  const float* xb = x + (size_t)b * 3 * 512 * 512;
  for (int j = 0; j < 8; ++j) {
    const int t = tg + j, hp = t >> 5, wp = t & 31;
    for (int idx = tid; idx < 768; idx += 128) {
      int c = idx >> 8, rem = idx & 255, p = rem >> 4, q = rem & 15;
      sp[j][idx] = xb[((size_t)c * 512 + hp * 16 + p) * 512 + wp * 16 + q];
    }
  }
  __syncthreads();
  float acc[8] = {0,0,0,0,0,0,0,0};
  const float* wr = pw + (size_t)tid * 768;
  for (int idx = 0; idx < 768; ++idx) {
    const float w = wr[idx];
#pragma unroll
    for (int j = 0; j < 8; ++j) acc[j] += w * sp[j][idx];
  }
  const float bias = pb[tid];
  const int wv = tid >> 6, ln = tid & 63;
#pragma unroll
  for (int j = 0; j < 8; ++j) {
    acc[j] += bias;
    float s = acc[j], sq = acc[j] * acc[j];
    for (int off = 32; off; off >>= 1) { s += __shfl_xor(s, off); sq += __shfl_xor(sq, off); }
    if (ln == 0) { red[wv][j][0] = s; red[wv][j][1] = sq; }
  }
  __syncthreads();
  const float gg = g[tid], bb = be[tid];
#pragma unroll
  for (int j = 0; j < 8; ++j) {
    float s  = red[0][j][0] + red[1][j][0];
    float sq = red[0][j][1] + red[1][j][1];
    float mean = s * (1.0f / 128.0f);
    float var  = sq * (1.0f / 128.0f) - mean * mean;
    float rstd = rsqrtf(var + EPS);
    tok[((size_t)(b * L + tg + j)) * DM + tid] = (acc[j] - mean) * rstd * gg + bb;
  }
}

// ---------------- fused layernorm + in_proj ----------------
// grid 2048 (8 tokens/block), 256 threads
__global__ __launch_bounds__(256) void k_inproj(const float* __restrict__ tok,
    const float* __restrict__ inw, const float* __restrict__ lg,
    const float* __restrict__ lb, float* __restrict__ zx){
  __shared__ float sx[8][128];
  const int blk = blockIdx.x, b = blk >> 7, tg = (blk & 127) << 3, tid = threadIdx.x;
  for (int i = tid; i < 1024; i += 256) {
    int j = i >> 7, d = i & 127;
    sx[j][d] = tok[((size_t)(b * L + tg + j)) * DM + d];
  }
  __syncthreads();
  {
    const int j = tid >> 5, ln = tid & 31;
    float v[4]; float s = 0, sq = 0;
#pragma unroll
    for (int k = 0; k < 4; ++k) { v[k] = sx[j][ln * 4 + k]; s += v[k]; sq += v[k] * v[k]; }
    for (int off = 16; off; off >>= 1) { s += __shfl_xor(s, off, 32); sq += __shfl_xor(sq, off, 32); }
    float mean = s * (1.f / 128.f), var = sq * (1.f / 128.f) - mean * mean;
    float rstd = rsqrtf(var + EPS);
#pragma unroll
    for (int k = 0; k < 4; ++k) { int d = ln * 4 + k; sx[j][d] = (v[k] - mean) * rstd * lg[d] + lb[d]; }
  }
  __syncthreads();
  for (int e = tid; e < DPROJ; e += 256) {
    const float* row = inw + (size_t)e * DM;
    float a[8] = {0,0,0,0,0,0,0,0};
    for (int d = 0; d < DM; ++d) {
      const float w = row[d];
#pragma unroll
      for (int j = 0; j < 8; ++j) a[j] += w * sx[j][d];
    }
#pragma unroll
    for (int j = 0; j < 8; ++j) zx[((size_t)(b * L + tg + j)) * DPROJ + e] = a[j];
  }
}

// ---------------- causal depthwise conv + silu ----------------
// grid B*L, 384 threads (one per conv channel)
__global__ __launch_bounds__(384) void k_conv(const float* __restrict__ zx,
    const float* __restrict__ cw, const float* __restrict__ cb, float* __restrict__ xc){
  const int b = blockIdx.x >> 10, l = blockIdx.x & 1023, ch = threadIdx.x;
  float acc = cb[ch];
  const float w0 = cw[ch * 4], w1 = cw[ch * 4 + 1], w2 = cw[ch * 4 + 2], w3 = cw[ch * 4 + 3];
  const float* base = zx + ((size_t)(b << 10)) * DPROJ + DI + ch;
  if (l >= 3) acc += base[(size_t)(l - 3) * DPROJ] * w0;
  if (l >= 2) acc += base[(size_t)(l - 2) * DPROJ] * w1;
  if (l >= 1) acc += base[(size_t)(l - 1) * DPROJ] * w2;
  acc += base[(size_t)l * DPROJ] * w3;
  acc = silu_f(acc);
  xc[((size_t)(b << 10) + l) * CDIM + ch] = acc;
}

// ---------------- sequential SSM scan ----------------
// grid 512 = (b,h,pgroup of 8), 64 threads; lane t: p = pg + (t>>3), n = (t&7)+8j
constexpr int CH = 64;
__global__ __launch_bounds__(64) void k_scan(const float* __restrict__ zx,
    const float* __restrict__ xc, const float* __restrict__ dtb,
    const float* __restrict__ Alog, const float* __restrict__ Dsk,
    float* __restrict__ ys){
  __shared__ float sB[CH][64], sC[CH][64], sX[CH][8];
  __shared__ float sdA[CH], sdt[CH];
  const int blk = blockIdx.x, b = blk >> 5, h = (blk >> 2) & 7, pg = (blk & 3) << 3;
  const int t = threadIdx.x, pl = t >> 3, nb = t & 7;
  float hs[8] = {0,0,0,0,0,0,0,0};
  const float dtbias = dtb[h], nA = -expf(Alog[h]), dsk = Dsk[h];
  for (int c0 = 0; c0 < L; c0 += CH) {
    __syncthreads();
    for (int i = t; i < CH * 64; i += 64) {
      int ll = i >> 6, n = i & 63;
      size_t rb = ((size_t)(b << 10) + c0 + ll) * CDIM;
      sB[ll][n] = xc[rb + DI + n];
      sC[ll][n] = xc[rb + DI + DS + n];
    }
    for (int i = t; i < CH * 8; i += 64) {
      int ll = i >> 3, pp = i & 7;
      sX[ll][pp] = xc[((size_t)(b << 10) + c0 + ll) * CDIM + (h << 5) + pg + pp];
    }
    for (int i = t; i < CH; i += 64) {
      float dr = zx[((size_t)(b << 10) + c0 + i) * DPROJ + 640 + h] + dtbias;
      float dt = dr > 20.f ? dr : log1pf(expf(dr));
      sdt[i] = dt; sdA[i] = expf(dt * nA);
    }
    __syncthreads();
    for (int s = 0; s < CH; ++s) {
      const float dA = sdA[s], dt = sdt[s], xp = sX[s][pl];
      const float coef = dt * xp;
      float yp = 0.f;
#pragma unroll
      for (int jj = 0; jj < 8; ++jj) {
        const int n = nb + (jj << 3);
        hs[jj] = hs[jj] * dA + coef * sB[s][n];
        yp += hs[jj] * sC[s][n];
      }
      yp += __shfl_xor(yp, 1); yp += __shfl_xor(yp, 2); yp += __shfl_xor(yp, 4);
      if (nb == 0) ys[((size_t)(b << 10) + c0 + s) * DI + (h << 5) + pg + pl] = yp + dsk * xp;
    }
  }
}

// ---------------- gate * silu(z), RMSNorm, out_proj, residual add ----------------
// grid 4096 (4 tokens/block), 256 threads
__global__ __launch_bounds__(256) void k_gateout(const float* __restrict__ zx,
    const float* __restrict__ ys, const float* __restrict__ nw,
    const float* __restrict__ ow, float* __restrict__ tok){
  __shared__ float sy[4][256];
  const int blk = blockIdx.x, b = blk >> 8, tg = (blk & 255) << 2, tid = threadIdx.x;
  for (int j = 0; j < 4; ++j) {
    size_t row = (size_t)(b << 10) + tg + j;
    float y = ys[row * DI + tid];
    float z = zx[row * DPROJ + tid];
    sy[j][tid] = y * silu_f(z);
  }
  __syncthreads();
  {
    const int j = tid >> 6, ln = tid & 63;
    float v[4]; float sq = 0;
#pragma unroll
    for (int k = 0; k < 4; ++k) { v[k] = sy[j][ln + (k << 6)]; sq += v[k] * v[k]; }
    for (int off = 32; off; off >>= 1) sq += __shfl_xor(sq, off);
    float rstd = rsqrtf(sq * (1.f / 256.f) + EPS);
#pragma unroll
    for (int k = 0; k < 4; ++k) { int e = ln + (k << 6); sy[j][e] = v[k] * rstd * nw[e]; }
  }
  __syncthreads();
  const int d = tid & 127, jh = tid >> 7;
  const float* row = ow + (size_t)d * DI;
  float a0 = 0, a1 = 0;
  for (int e = 0; e < DI; ++e) { float w = row[e]; a0 += w * sy[jh][e]; a1 += w * sy[jh + 2][e]; }
  tok[((size_t)(b << 10) + tg + jh) * DM + d]     += a0;
  tok[((size_t)(b << 10) + tg + jh + 2) * DM + d] += a1;
}

// ---------------- final LN + attention scores ----------------
// grid 2048 (8 tokens/block), 128 threads
__global__ __launch_bounds__(128) void k_score(const float* __restrict__ tok,
    const float* __restrict__ fg, const float* __restrict__ fb,
    const float* __restrict__ w1, const float* __restrict__ b1,
    const float* __restrict__ w2, const float* __restrict__ b2,
    float* __restrict__ tokF, float* __restrict__ sc){
  __shared__ float st[8][128];
  __shared__ float sh[8][64];
  const int blk = blockIdx.x, b = blk >> 7, tg = (blk & 127) << 3, tid = threadIdx.x;
  for (int i = tid; i < 1024; i += 128) {
    int j = i >> 7, d = i & 127;
    st[j][d] = tok[((size_t)(b << 10) + tg + j) * DM + d];
  }
  __syncthreads();
  {
    const int j = tid >> 4, ln = tid & 15;
    float v[8]; float s = 0, sq = 0;
#pragma unroll
    for (int k = 0; k < 8; ++k) { v[k] = st[j][ln + (k << 4)]; s += v[k]; sq += v[k] * v[k]; }
    for (int off = 8; off; off >>= 1) { s += __shfl_xor(s, off, 16); sq += __shfl_xor(sq, off, 16); }
    float mean = s * (1.f / 128.f), var = sq * (1.f / 128.f) - mean * mean;
    float rstd = rsqrtf(var + EPS);
#pragma unroll
    for (int k = 0; k < 8; ++k) {
      int d = ln + (k << 4);
      float o = (v[k] - mean) * rstd * fg[d] + fb[d];
      st[j][d] = o;
      tokF[((size_t)(b << 10) + tg + j) * DM + d] = o;
    }
  }
  __syncthreads();
  {
    const int hh = tid & 63, jh = tid >> 6;
    const float* row = w1 + (size_t)hh * DM;
    const float bb = b1[hh];
    for (int jj = jh; jj < 8; jj += 2) {
      float a = bb;
      for (int d = 0; d < DM; ++d) a += row[d] * st[jj][d];
      sh[jj][hh] = tanhf(a);
    }
  }
  __syncthreads();
  if (tid < 8) {
    float a = b2[0];
    for (int k = 0; k < 64; ++k) a += sh[tid][k] * w2[k];
    sc[(size_t)(b << 10) + tg + tid] = a;
  }
}

// ---------------- softmax pool + l2 normalize ----------------
// grid 16, 256 threads
__global__ __launch_bounds__(256) void k_pool(const float* __restrict__ tokF,
    const float* __restrict__ sc, float* __restrict__ out){
  __shared__ float sw[1024];
  __shared__ float sred[4];
  __shared__ float sp[2][128];
  const int b = blockIdx.x, tid = threadIdx.x, wv = tid >> 6, ln = tid & 63;
  const float* s = sc + ((size_t)b << 10);
  float mx = -1e30f;
  for (int l = tid; l < 1024; l += 256) mx = fmaxf(mx, s[l]);
  for (int off = 32; off; off >>= 1) mx = fmaxf(mx, __shfl_xor(mx, off));
  if (ln == 0) sred[wv] = mx;
  __syncthreads();
  mx = fmaxf(fmaxf(sred[0], sred[1]), fmaxf(sred[2], sred[3]));
  float se = 0;
  for (int l = tid; l < 1024; l += 256) { float e = expf(s[l] - mx); sw[l] = e; se += e; }
  for (int off = 32; off; off >>= 1) se += __shfl_xor(se, off);
  __syncthreads();
  if (ln == 0) sred[wv] = se;
  __syncthreads();
  se = sred[0] + sred[1] + sred[2] + sred[3];
  const float inv = 1.f / se;
  const int d = tid & 127, hf = tid >> 7;
  float acc = 0;
  const float* tf = tokF + ((size_t)b << 10) * DM;
  for (int l = hf * 512; l < (hf + 1) * 512; ++l) acc += sw[l] * tf[(size_t)l * DM + d];
  sp[hf][d] = acc;
  __syncthreads();
  if (tid < 128) sp[0][tid] = (sp[0][tid] + sp[1][tid]) * inv;
  __syncthreads();
  if (tid < 64) {
    float v0 = sp[0][tid], v1 = sp[0][tid + 64];
    float sq = v0 * v0 + v1 * v1;
    for (int off = 32; off; off >>= 1) sq += __shfl_xor(sq, off);
    float nrm = fmaxf(sqrtf(sq), 1e-12f);
    out[(size_t)b * DM + tid]      = v0 / nrm;
    out[(size_t)b * DM + tid + 64] = v1 / nrm;
  }
}

extern "C" void kernel_launch(void* const* d_in, const int* in_sizes, int n_in,
                              void* d_out, int out_size, void* d_ws, size_t ws_size,
                              hipStream_t stream) {
  const float* x       = (const float*)d_in[0];
  const float* patch_w = (const float*)d_in[1];
  const float* patch_b = (const float*)d_in[2];
  const float* pe_g    = (const float*)d_in[3];
  const float* pe_b    = (const float*)d_in[4];
  const float* in_w    = (const float*)d_in[5];
  const float* conv_w  = (const float*)d_in[6];
  const float* conv_b  = (const float*)d_in[7];
  const float* dt_bias = (const float*)d_in[8];
  const float* A_log   = (const float*)d_in[9];
  const float* D_skip  = (const float*)d_in[10];
  const float* nw      = (const float*)d_in[11];
  const float* out_w   = (const float*)d_in[12];
  const float* ln_g    = (const float*)d_in[13];
  const float* ln_b    = (const float*)d_in[14];
  const float* fn_g    = (const float*)d_in[15];
  const float* fn_b    = (const float*)d_in[16];
  const float* w1      = (const float*)d_in[17];
  const float* b1      = (const float*)d_in[18];
  const float* w2      = (const float*)d_in[19];
  const float* b2      = (const float*)d_in[20];
  float* out = (float*)d_out;
  char* ws = (char*)d_ws;

  // workspace layout
  float* tok  = (float*)(ws);                          //  8 MB  (B*L*128)
  float* zx   = (float*)(ws + (size_t)8  * 1024 * 1024);  // 42.5 MB (B*L*648)
  float* xcb  = (float*)(ws + (size_t)51 * 1024 * 1024);  // 25 MB  (B*L*384)
  float* ysb  = (float*)(ws + (size_t)76 * 1024 * 1024);  // 16 MB  (B*L*256)
  // after the layer loop zx is dead -> reuse its space for tokF and scores
  float* tokF = zx;                                       //  8 MB
  float* scb  = (float*)(ws + (size_t)(8 + 9) * 1024 * 1024); // 64 KB (inside zx region)

  k_patch<<<2048, 128, 0, stream>>>(x, patch_w, patch_b, pe_g, pe_b, tok);
  for (int ly = 0; ly < 4; ++ly) {
    k_inproj<<<2048, 256, 0, stream>>>(tok, in_w + (size_t)ly * DPROJ * DM,
                                       ln_g + ly * DM, ln_b + ly * DM, zx);
    k_conv<<<NB * L, CDIM, 0, stream>>>(zx, conv_w + (size_t)ly * CDIM * 4,
                                        conv_b + ly * CDIM, xcb);
    k_scan<<<512, 64, 0, stream>>>(zx, xcb, dt_bias + ly * NH, A_log + ly * NH,
                                   D_skip + ly * NH, ysb);
    k_gateout<<<4096, 256, 0, stream>>>(zx, ysb, nw + ly * DI,
                                        out_w + (size_t)ly * DM * DI, tok);
  }
  k_score<<<2048, 128, 0, stream>>>(tok, fn_g, fn_b, w1, b1, w2, b2, tokF, scb);
  k_pool<<<16, 256, 0, stream>>>(tokF, scb, out);
}

// Round 2
// 1835.650 us; speedup vs baseline: 1.4825x; 1.4825x over previous
//
#include <hip/hip_runtime.h>
#include <math.h>

#define EPS 1e-5f

// Model dims
constexpr int NB      = 16;    // batch
constexpr int L       = 1024;  // tokens (32x32 patches)
constexpr int DM      = 128;   // d_model
constexpr int DI      = 256;   // d_inner
constexpr int DS      = 64;    // d_state
constexpr int NH      = 8;     // heads
constexpr int HD      = 32;    // head dim
constexpr int DPROJ   = 648;   // 2*DI + 2*DS + NH
constexpr int CDIM    = 384;   // DI + 2*DS

__device__ __forceinline__ float silu_f(float x){ return x / (1.f + expf(-x)); }

// ---------------- patch embed + pos layernorm ----------------
__global__ __launch_bounds__(128) void k_patch(const float* __restrict__ x,
    const float* __restrict__ pw, const float* __restrict__ pb,
    const float* __restrict__ g, const float* __restrict__ be,
    float* __restrict__ tok){
  __shared__ float sp[8][768];
  __shared__ float red[2][8][2];
  const int blk = blockIdx.x;
  const int b  = blk >> 7;
  const int tg = (blk & 127) << 3;
  const int tid = threadIdx.x;
  const float* xb = x + (size_t)b * 3 * 512 * 512;
  for (int j = 0; j < 8; ++j) {
    const int t = tg + j, hp = t >> 5, wp = t & 31;
    for (int idx = tid; idx < 768; idx += 128) {
      int c = idx >> 8, rem = idx & 255, p = rem >> 4, q = rem & 15;
      sp[j][idx] = xb[((size_t)c * 512 + hp * 16 + p) * 512 + wp * 16 + q];
    }
  }
  __syncthreads();
  float acc[8] = {0,0,0,0,0,0,0,0};
  const float* wr = pw + (size_t)tid * 768;
  for (int idx = 0; idx < 768; ++idx) {
    const float w = wr[idx];
#pragma unroll
    for (int j = 0; j < 8; ++j) acc[j] += w * sp[j][idx];
  }
  const float bias = pb[tid];
  const int wv = tid >> 6, ln = tid & 63;
#pragma unroll
  for (int j = 0; j < 8; ++j) {
    acc[j] += bias;
    float s = acc[j], sq = acc[j] * acc[j];
    for (int off = 32; off; off >>= 1) { s += __shfl_xor(s, off); sq += __shfl_xor(sq, off); }
    if (ln == 0) { red[wv][j][0] = s; red[wv][j][1] = sq; }
  }
  __syncthreads();
  const float gg = g[tid], bb = be[tid];
#pragma unroll
  for (int j = 0; j < 8; ++j) {
    float s  = red[0][j][0] + red[1][j][0];
    float sq = red[0][j][1] + red[1][j][1];
    float mean = s * (1.0f / 128.0f);
    float var  = sq * (1.0f / 128.0f) - mean * mean;
    float rstd = rsqrtf(var + EPS);
    tok[((size_t)(b * L + tg + j)) * DM + tid] = (acc[j] - mean) * rstd * gg + bb;
  }
}

// ---------------- fused layernorm + in_proj ----------------
__global__ __launch_bounds__(256) void k_inproj(const float* __restrict__ tok,
    const float* __restrict__ inw, const float* __restrict__ lg,
    const float* __restrict__ lb, float* __restrict__ zx){
  __shared__ float sx[8][128];
  const int blk = blockIdx.x, b = blk >> 7, tg = (blk & 127) << 3, tid = threadIdx.x;
  for (int i = tid; i < 1024; i += 256) {
    int j = i >> 7, d = i & 127;
    sx[j][d] = tok[((size_t)(b * L + tg + j)) * DM + d];
  }
  __syncthreads();
  {
    const int j = tid >> 5, ln = tid & 31;
    float v[4]; float s = 0, sq = 0;
#pragma unroll
    for (int k = 0; k < 4; ++k) { v[k] = sx[j][ln * 4 + k]; s += v[k]; sq += v[k] * v[k]; }
    for (int off = 16; off; off >>= 1) { s += __shfl_xor(s, off, 32); sq += __shfl_xor(sq, off, 32); }
    float mean = s * (1.f / 128.f), var = sq * (1.f / 128.f) - mean * mean;
    float rstd = rsqrtf(var + EPS);
#pragma unroll
    for (int k = 0; k < 4; ++k) { int d = ln * 4 + k; sx[j][d] = (v[k] - mean) * rstd * lg[d] + lb[d]; }
  }
  __syncthreads();
  for (int e = tid; e < DPROJ; e += 256) {
    const float* row = inw + (size_t)e * DM;
    float a[8] = {0,0,0,0,0,0,0,0};
    for (int d = 0; d < DM; ++d) {
      const float w = row[d];
#pragma unroll
      for (int j = 0; j < 8; ++j) a[j] += w * sx[j][d];
    }
#pragma unroll
    for (int j = 0; j < 8; ++j) zx[((size_t)(b * L + tg + j)) * DPROJ + e] = a[j];
  }
}

// ---------------- causal depthwise conv + silu ----------------
__global__ __launch_bounds__(384) void k_conv(const float* __restrict__ zx,
    const float* __restrict__ cw, const float* __restrict__ cb, float* __restrict__ xc){
  const int b = blockIdx.x >> 10, l = blockIdx.x & 1023, ch = threadIdx.x;
  float acc = cb[ch];
  const float w0 = cw[ch * 4], w1 = cw[ch * 4 + 1], w2 = cw[ch * 4 + 2], w3 = cw[ch * 4 + 3];
  const float* base = zx + ((size_t)(b << 10)) * DPROJ + DI + ch;
  if (l >= 3) acc += base[(size_t)(l - 3) * DPROJ] * w0;
  if (l >= 2) acc += base[(size_t)(l - 2) * DPROJ] * w1;
  if (l >= 1) acc += base[(size_t)(l - 1) * DPROJ] * w2;
  acc += base[(size_t)l * DPROJ] * w3;
  acc = silu_f(acc);
  xc[((size_t)(b << 10) + l) * CDIM + ch] = acc;
}

// ---------------- SSD step 1: dt, within-chunk cumulative log-decay ----------------
// grid: NB*NH*16 chunks, 64 threads (one per step in chunk)
__global__ __launch_bounds__(64) void k_dt(const float* __restrict__ zx,
    const float* __restrict__ dtbias, const float* __restrict__ Alog,
    float* __restrict__ dtb, float* __restrict__ lcb, float* __restrict__ Acb){
  const int blk = blockIdx.x;            // b*128 + h*16 + c
  const int c = blk & 15, h = (blk >> 4) & 7, b = blk >> 7;
  const int s = threadIdx.x;
  const int l = (c << 6) + s;
  float raw = zx[((size_t)(b << 10) + l) * DPROJ + 640 + h] + dtbias[h];
  float dt = raw > 20.f ? raw : log1pf(expf(raw));
  float la = dt * (-expf(Alog[h]));
  float cum = la;
  for (int off = 1; off < 64; off <<= 1) {
    float v = __shfl_up(cum, off, 64);
    if (s >= off) cum += v;
  }
  size_t o = ((size_t)((b << 3) + h) << 10) + l;
  dtb[o] = dt; lcb[o] = cum;
  if (s == 63) Acb[blk] = expf(cum);
}

// ---------------- SSD step 2: per-chunk state contribution S_c = sum_s coef_s x_s B_s^T ----------------
// grid: NB*NH*16, 256 threads; thread owns (p = tid>>3, n8 = (tid&7)*8)
__global__ __launch_bounds__(256) void k_cstate(const float* __restrict__ xc,
    const float* __restrict__ dtb, const float* __restrict__ lcb,
    float* __restrict__ Sc){
  __shared__ float sB[64][64];
  __shared__ float sX[64][32];
  __shared__ float scoef[64];
  const int blk = blockIdx.x;
  const int c = blk & 15, h = (blk >> 4) & 7, b = blk >> 7;
  const int tid = threadIdx.x;
  const int l0 = c << 6;
  for (int i = tid; i < 64 * 16; i += 256) {
    int r = i >> 4, q = i & 15;
    float4 v = *(const float4*)(xc + ((size_t)(b << 10) + l0 + r) * CDIM + DI + q * 4);
    *(float4*)(&sB[r][q * 4]) = v;
  }
  for (int i = tid; i < 64 * 8; i += 256) {
    int r = i >> 3, q = i & 7;
    float4 v = *(const float4*)(xc + ((size_t)(b << 10) + l0 + r) * CDIM + (h << 5) + q * 4);
    *(float4*)(&sX[r][q * 4]) = v;
  }
  if (tid < 64) {
    size_t o = ((size_t)((b << 3) + h) << 10) + l0;
    float lcT = lcb[o + 63];
    scoef[tid] = dtb[o + tid] * __expf(lcT - lcb[o + tid]);   // arg <= 0 always
  }
  __syncthreads();
  const int p = tid >> 3, n8 = (tid & 7) << 3;
  float S[8] = {0,0,0,0,0,0,0,0};
  for (int s = 0; s < 64; ++s) {
    const float cf = scoef[s] * sX[s][p];
#pragma unroll
    for (int j = 0; j < 8; ++j) S[j] += cf * sB[s][n8 + j];
  }
  float* dst = Sc + ((size_t)blk << 11) + (p << 6) + n8;
  *(float4*)dst       = make_float4(S[0], S[1], S[2], S[3]);
  *(float4*)(dst + 4) = make_float4(S[4], S[5], S[6], S[7]);
}

// ---------------- SSD step 3: inter-chunk scan (in place: Sc[c] becomes h0 before chunk c) ----------------
// grid: NB*NH*8 = 1024, 256 threads; thread owns one of 2048 state elems of one (b,h)
__global__ __launch_bounds__(256) void k_hscan(float* __restrict__ Sc, const float* __restrict__ Acb){
  const int blk = blockIdx.x;
  const int bh = blk >> 3;
  const int e = ((blk & 7) << 8) + threadIdx.x;
  float hs = 0.f;
  const size_t base = ((size_t)bh << 15) + e;
  for (int c = 0; c < 16; ++c) {
    const size_t o = base + ((size_t)c << 11);
    float v = Sc[o];
    Sc[o] = hs;
    hs = Acb[(bh << 4) + c] * hs + v;
  }
}

// ---------------- SSD step 4: within-chunk outputs ----------------
// grid: NB*NH*16, 256 threads; thread (t = tid&63, pg = (tid>>6)*8) computes y[t][pg..pg+7]
__global__ __launch_bounds__(256) void k_chunky(const float* __restrict__ xc,
    const float* __restrict__ h0buf, const float* __restrict__ dtb,
    const float* __restrict__ lcb, const float* __restrict__ Dsk,
    float* __restrict__ ys){
  __shared__ float sC[64][65];
  __shared__ float sB[64][64];
  __shared__ float sX[64][33];
  __shared__ float sH[32][64];
  __shared__ float sdt[64], slc[64];
  const int blk = blockIdx.x;
  const int c = blk & 15, h = (blk >> 4) & 7, b = blk >> 7;
  const int tid = threadIdx.x;
  const int l0 = c << 6;
  for (int i = tid; i < 64 * 16; i += 256) {
    int r = i >> 4, q = i & 15;
    size_t rowb = ((size_t)(b << 10) + l0 + r) * CDIM;
    float4 vb = *(const float4*)(xc + rowb + DI + q * 4);
    float4 vc = *(const float4*)(xc + rowb + DI + DS + q * 4);
    *(float4*)(&sB[r][q * 4]) = vb;
    sC[r][q * 4] = vc.x; sC[r][q * 4 + 1] = vc.y; sC[r][q * 4 + 2] = vc.z; sC[r][q * 4 + 3] = vc.w;
  }
  for (int i = tid; i < 64 * 8; i += 256) {
    int r = i >> 3, q = i & 7;
    float4 v = *(const float4*)(xc + ((size_t)(b << 10) + l0 + r) * CDIM + (h << 5) + q * 4);
    sX[r][q * 4] = v.x; sX[r][q * 4 + 1] = v.y; sX[r][q * 4 + 2] = v.z; sX[r][q * 4 + 3] = v.w;
  }
  for (int i = tid; i < 512; i += 256) {
    float4 v = *(const float4*)(h0buf + ((size_t)blk << 11) + i * 4);
    *(float4*)(&sH[0][0] + i * 4) = v;
  }
  if (tid < 64) {
    size_t o = ((size_t)((b << 3) + h) << 10) + l0;
    sdt[tid] = dtb[o + tid];
    slc[tid] = lcb[o + tid];
  }
  __syncthreads();
  const int t = tid & 63, pg = (tid >> 6) << 3;
  float Creg[64];
#pragma unroll
  for (int n = 0; n < 64; ++n) Creg[n] = sC[t][n];
  const float lct = slc[t];
  const float Pt = __expf(lct);
  float y[8];
#pragma unroll
  for (int j = 0; j < 8; ++j) {
    float a = 0.f;
#pragma unroll
    for (int n = 0; n < 64; ++n) a += sH[pg + j][n] * Creg[n];
    y[j] = Pt * a;
  }
  for (int s = 0; s < 64; ++s) {
    float g = 0.f;
#pragma unroll
    for (int n = 0; n < 64; ++n) g += Creg[n] * sB[s][n];
    float m = (s <= t) ? 1.f : 0.f;
    float w = m * sdt[s] * __expf(fminf(lct - slc[s], 0.f)) * g;
#pragma unroll
    for (int j = 0; j < 8; ++j) y[j] += w * sX[s][pg + j];
  }
  const float dsk = Dsk[h];
  float* dst = ys + ((size_t)(b << 10) + l0 + t) * DI + (h << 5) + pg;
#pragma unroll
  for (int j = 0; j < 8; ++j) dst[j] = y[j] + dsk * sX[t][pg + j];
}

// ---------------- gate * silu(z), RMSNorm, out_proj, residual add ----------------
__global__ __launch_bounds__(256) void k_gateout(const float* __restrict__ zx,
    const float* __restrict__ ys, const float* __restrict__ nw,
    const float* __restrict__ ow, float* __restrict__ tok){
  __shared__ float sy[4][256];
  const int blk = blockIdx.x, b = blk >> 8, tg = (blk & 255) << 2, tid = threadIdx.x;
  for (int j = 0; j < 4; ++j) {
    size_t row = (size_t)(b << 10) + tg + j;
    float y = ys[row * DI + tid];
    float z = zx[row * DPROJ + tid];
    sy[j][tid] = y * silu_f(z);
  }
  __syncthreads();
  {
    const int j = tid >> 6, ln = tid & 63;
    float v[4]; float sq = 0;
#pragma unroll
    for (int k = 0; k < 4; ++k) { v[k] = sy[j][ln + (k << 6)]; sq += v[k] * v[k]; }
    for (int off = 32; off; off >>= 1) sq += __shfl_xor(sq, off);
    float rstd = rsqrtf(sq * (1.f / 256.f) + EPS);
#pragma unroll
    for (int k = 0; k < 4; ++k) { int e = ln + (k << 6); sy[j][e] = v[k] * rstd * nw[e]; }
  }
  __syncthreads();
  const int d = tid & 127, jh = tid >> 7;
  const float* row = ow + (size_t)d * DI;
  float a0 = 0, a1 = 0;
  for (int e = 0; e < DI; ++e) { float w = row[e]; a0 += w * sy[jh][e]; a1 += w * sy[jh + 2][e]; }
  tok[((size_t)(b << 10) + tg + jh) * DM + d]     += a0;
  tok[((size_t)(b << 10) + tg + jh + 2) * DM + d] += a1;
}

// ---------------- final LN + attention scores ----------------
__global__ __launch_bounds__(128) void k_score(const float* __restrict__ tok,
    const float* __restrict__ fg, const float* __restrict__ fb,
    const float* __restrict__ w1, const float* __restrict__ b1,
    const float* __restrict__ w2, const float* __restrict__ b2,
    float* __restrict__ tokF, float* __restrict__ sc){
  __shared__ float st[8][128];
  __shared__ float sh[8][64];
  const int blk = blockIdx.x, b = blk >> 7, tg = (blk & 127) << 3, tid = threadIdx.x;
  for (int i = tid; i < 1024; i += 128) {
    int j = i >> 7, d = i & 127;
    st[j][d] = tok[((size_t)(b << 10) + tg + j) * DM + d];
  }
  __syncthreads();
  {
    const int j = tid >> 4, ln = tid & 15;
    float v[8]; float s = 0, sq = 0;
#pragma unroll
    for (int k = 0; k < 8; ++k) { v[k] = st[j][ln + (k << 4)]; s += v[k]; sq += v[k] * v[k]; }
    for (int off = 8; off; off >>= 1) { s += __shfl_xor(s, off, 16); sq += __shfl_xor(sq, off, 16); }
    float mean = s * (1.f / 128.f), var = sq * (1.f / 128.f) - mean * mean;
    float rstd = rsqrtf(var + EPS);
#pragma unroll
    for (int k = 0; k < 8; ++k) {
      int d = ln + (k << 4);
      float o = (v[k] - mean) * rstd * fg[d] + fb[d];
      st[j][d] = o;
      tokF[((size_t)(b << 10) + tg + j) * DM + d] = o;
    }
  }
  __syncthreads();
  {
    const int hh = tid & 63, jh = tid >> 6;
    const float* row = w1 + (size_t)hh * DM;
    const float bb = b1[hh];
    for (int jj = jh; jj < 8; jj += 2) {
      float a = bb;
      for (int d = 0; d < DM; ++d) a += row[d] * st[jj][d];
      sh[jj][hh] = tanhf(a);
    }
  }
  __syncthreads();
  if (tid < 8) {
    float a = b2[0];
    for (int k = 0; k < 64; ++k) a += sh[tid][k] * w2[k];
    sc[(size_t)(b << 10) + tg + tid] = a;
  }
}

// ---------------- softmax pool + l2 normalize ----------------
__global__ __launch_bounds__(256) void k_pool(const float* __restrict__ tokF,
    const float* __restrict__ sc, float* __restrict__ out){
  __shared__ float sw[1024];
  __shared__ float sred[4];
  __shared__ float sp[2][128];
  const int b = blockIdx.x, tid = threadIdx.x, wv = tid >> 6, ln = tid & 63;
  const float* s = sc + ((size_t)b << 10);
  float mx = -1e30f;
  for (int l = tid; l < 1024; l += 256) mx = fmaxf(mx, s[l]);
  for (int off = 32; off; off >>= 1) mx = fmaxf(mx, __shfl_xor(mx, off));
  if (ln == 0) sred[wv] = mx;
  __syncthreads();
  mx = fmaxf(fmaxf(sred[0], sred[1]), fmaxf(sred[2], sred[3]));
  float se = 0;
  for (int l = tid; l < 1024; l += 256) { float e = expf(s[l] - mx); sw[l] = e; se += e; }
  for (int off = 32; off; off >>= 1) se += __shfl_xor(se, off);
  __syncthreads();
  if (ln == 0) sred[wv] = se;
  __syncthreads();
  se = sred[0] + sred[1] + sred[2] + sred[3];
  const float inv = 1.f / se;
  const int d = tid & 127, hf = tid >> 7;
  float acc = 0;
  const float* tf = tokF + ((size_t)b << 10) * DM;
  for (int l = hf * 512; l < (hf + 1) * 512; ++l) acc += sw[l] * tf[(size_t)l * DM + d];
  sp[hf][d] = acc;
  __syncthreads();
  if (tid < 128) sp[0][tid] = (sp[0][tid] + sp[1][tid]) * inv;
  __syncthreads();
  if (tid < 64) {
    float v0 = sp[0][tid], v1 = sp[0][tid + 64];
    float sq = v0 * v0 + v1 * v1;
    for (int off = 32; off; off >>= 1) sq += __shfl_xor(sq, off);
    float nrm = fmaxf(sqrtf(sq), 1e-12f);
    out[(size_t)b * DM + tid]      = v0 / nrm;
    out[(size_t)b * DM + tid + 64] = v1 / nrm;
  }
}

extern "C" void kernel_launch(void* const* d_in, const int* in_sizes, int n_in,
                              void* d_out, int out_size, void* d_ws, size_t ws_size,
                              hipStream_t stream) {
  const float* x       = (const float*)d_in[0];
  const float* patch_w = (const float*)d_in[1];
  const float* patch_b = (const float*)d_in[2];
  const float* pe_g    = (const float*)d_in[3];
  const float* pe_b    = (const float*)d_in[4];
  const float* in_w    = (const float*)d_in[5];
  const float* conv_w  = (const float*)d_in[6];
  const float* conv_b  = (const float*)d_in[7];
  const float* dt_bias = (const float*)d_in[8];
  const float* A_log   = (const float*)d_in[9];
  const float* D_skip  = (const float*)d_in[10];
  const float* nw      = (const float*)d_in[11];
  const float* out_w   = (const float*)d_in[12];
  const float* ln_g    = (const float*)d_in[13];
  const float* ln_b    = (const float*)d_in[14];
  const float* fn_g    = (const float*)d_in[15];
  const float* fn_b    = (const float*)d_in[16];
  const float* w1      = (const float*)d_in[17];
  const float* b1      = (const float*)d_in[18];
  const float* w2      = (const float*)d_in[19];
  const float* b2      = (const float*)d_in[20];
  float* out = (float*)d_out;
  char* ws = (char*)d_ws;

  // workspace layout (bytes)
  size_t off = 0;
  float* tok  = (float*)(ws + off); off += (size_t)NB * L * DM * 4;       //  8 MB
  float* zx   = (float*)(ws + off); off += (size_t)NB * L * DPROJ * 4;    // 40.5 MB
  float* xcb  = (float*)(ws + off); off += (size_t)NB * L * CDIM * 4;     // 24 MB
  float* ysb  = (float*)(ws + off); off += (size_t)NB * L * DI * 4;       // 16 MB
  float* Scb  = (float*)(ws + off); off += (size_t)NB * NH * 16 * 2048 * 4; // 16 MB (S_c, then h0 in-place)
  float* dtb  = (float*)(ws + off); off += (size_t)NB * NH * L * 4;       // 0.5 MB
  float* lcb  = (float*)(ws + off); off += (size_t)NB * NH * L * 4;       // 0.5 MB
  float* Acb  = (float*)(ws + off); off += (size_t)NB * NH * 16 * 4;      // 8 KB
  // final stage reuses zx region (dead after the layer loop)
  float* tokF = zx;
  float* scb  = (float*)(ws + (size_t)18 * 1024 * 1024 + 8 * 1024 * 1024); // inside zx, past tokF

  k_patch<<<2048, 128, 0, stream>>>(x, patch_w, patch_b, pe_g, pe_b, tok);
  for (int ly = 0; ly < 4; ++ly) {
    k_inproj<<<2048, 256, 0, stream>>>(tok, in_w + (size_t)ly * DPROJ * DM,
                                       ln_g + ly * DM, ln_b + ly * DM, zx);
    k_conv<<<NB * L, CDIM, 0, stream>>>(zx, conv_w + (size_t)ly * CDIM * 4,
                                        conv_b + ly * CDIM, xcb);
    k_dt<<<NB * NH * 16, 64, 0, stream>>>(zx, dt_bias + ly * NH, A_log + ly * NH,
                                          dtb, lcb, Acb);
    k_cstate<<<NB * NH * 16, 256, 0, stream>>>(xcb, dtb, lcb, Scb);
    k_hscan<<<NB * NH * 8, 256, 0, stream>>>(Scb, Acb);
    k_chunky<<<NB * NH * 16, 256, 0, stream>>>(xcb, Scb, dtb, lcb,
                                               D_skip + ly * NH, ysb);
    k_gateout<<<4096, 256, 0, stream>>>(zx, ysb, nw + ly * DI,
                                        out_w + (size_t)ly * DM * DI, tok);
  }
  k_score<<<2048, 128, 0, stream>>>(tok, fn_g, fn_b, w1, b1, w2, b2, tokF, scb);
  k_pool<<<16, 256, 0, stream>>>(tokF, scb, out);
}

// Round 3
// 864.640 us; speedup vs baseline: 3.1473x; 2.1230x over previous
//
#include <hip/hip_runtime.h>
#include <math.h>

#define EPS 1e-5f

constexpr int NB      = 16;
constexpr int L       = 1024;
constexpr int DM      = 128;
constexpr int DI      = 256;
constexpr int DS      = 64;
constexpr int NH      = 8;
constexpr int DPROJ   = 648;   // 2*DI + 2*DS + NH
constexpr int CDIM    = 384;   // DI + 2*DS
constexpr int EPAD    = 656;   // DPROJ padded to 41*16

typedef __attribute__((ext_vector_type(8))) short short8v;
typedef __attribute__((ext_vector_type(4))) float f32x4;
typedef unsigned short ushort_t;

__device__ __forceinline__ float silu_f(float x){ return x / (1.f + expf(-x)); }
__device__ __forceinline__ ushort_t f2bf(float f){
  union { float f; unsigned int u; } v; v.f = f;
  unsigned int r = v.u + 0x7FFF + ((v.u >> 16) & 1);
  return (ushort_t)(r >> 16);
}

// ---------------- weight conversion / folding (runs once per launch) ----------------
// inwb[ly][e][d] = bf16(in_w * ln_g[d])  (e<648, padded to 656 with 0)
// biasin[ly][e]  = sum_d in_w[e][d]*ln_b[d]
// owb[ly][d][e]  = bf16(out_w * nw[e])
// pwb[n][k]      = bf16(patch_w)
__global__ __launch_bounds__(256) void k_cvt(const float* __restrict__ in_w,
    const float* __restrict__ ln_g, const float* __restrict__ ln_b,
    const float* __restrict__ out_w, const float* __restrict__ nw,
    const float* __restrict__ patch_w,
    ushort_t* __restrict__ inwb, ushort_t* __restrict__ owb,
    ushort_t* __restrict__ pwb, float* __restrict__ biasin){
  const int R1 = 4 * EPAD * 128, R2 = 4 * 128 * 256, R3 = 128 * 768, R4 = 4 * EPAD;
  int i = blockIdx.x * 256 + threadIdx.x;
  if (i < R1) {
    int ly = i / (EPAD * 128), rem = i % (EPAD * 128), e = rem >> 7, d = rem & 127;
    float v = 0.f;
    if (e < DPROJ) v = in_w[((size_t)ly * DPROJ + e) * 128 + d] * ln_g[ly * 128 + d];
    inwb[i] = f2bf(v);
    return;
  }
  i -= R1;
  if (i < R2) {
    int ly = i >> 15, rem = i & 32767, e = rem & 255;
    owb[i] = f2bf(out_w[i] * nw[ly * 256 + e]);
    return;
  }
  i -= R2;
  if (i < R3) { pwb[i] = f2bf(patch_w[i]); return; }
  i -= R3;
  if (i < R4) {
    int ly = i / EPAD, e = i % EPAD;
    float s = 0.f;
    if (e < DPROJ) {
      const float* r = in_w + ((size_t)ly * DPROJ + e) * 128;
      const float* b = ln_b + ly * 128;
      for (int d = 0; d < 128; ++d) s += r[d] * b[d];
    }
    biasin[i] = s;
  }
}

// ---------------- patch embed (MFMA, K=768 in 6 chunks) + pos layernorm ----------------
// grid 256 (64 tokens/block), 256 threads (4 waves = 4 m-tiles of 16)
__global__ __launch_bounds__(256) void k_patch(const float* __restrict__ x,
    const ushort_t* __restrict__ pwb, const float* __restrict__ pb,
    const float* __restrict__ pg, const float* __restrict__ pbe,
    float* __restrict__ tok){
  __shared__ ushort_t Al[64 * 128];
  __shared__ ushort_t Bl[128 * 128];
  __shared__ float spb[128], spg[128], spe[128];
  const int m0 = blockIdx.x * 64;
  const int tid = threadIdx.x;
  char* Ab = (char*)Al; char* Bb = (char*)Bl;
  if (tid < 128) { spb[tid] = pb[tid]; spg[tid] = pg[tid]; spe[tid] = pbe[tid]; }
  const int w = tid >> 6, l = tid & 63, lr = l & 15, lgp = l >> 4;
  f32x4 acc[8];
#pragma unroll
  for (int nt = 0; nt < 8; ++nt) acc[nt] = (f32x4){0.f, 0.f, 0.f, 0.f};
  for (int kc = 0; kc < 6; ++kc) {
    __syncthreads();
    // stage B chunk: rows n=0..127, k = kc*128..+128
    for (int idx = tid; idx < 128 * 16; idx += 256) {
      int n = idx >> 4, ch = idx & 15;
      short8v v = *(const short8v*)(pwb + (size_t)n * 768 + kc * 128 + (ch << 3));
      *(short8v*)(Bb + n * 256 + ((ch * 16) ^ ((n & 7) << 4))) = v;
    }
    // stage A chunk (im2col): channel kc>>1, rows (kc&1)*8 .. +8
    {
      const int c = kc >> 1;
      for (int i = tid; i < 1024; i += 256) {
        int t = i >> 4, p = (i >> 1) & 7, o = i & 1;
        int T = m0 + t, bb = T >> 10, tl = T & 1023, hp = tl >> 5, wp = tl & 31;
        const float* src = x + (((size_t)(bb * 3 + c) * 512 + hp * 16 + ((kc & 1) << 3) + p) * 512
                                + wp * 16 + o * 8);
        float4 f0 = *(const float4*)src;
        float4 f1 = *(const float4*)(src + 4);
        short8v v;
        v[0] = (short)f2bf(f0.x); v[1] = (short)f2bf(f0.y); v[2] = (short)f2bf(f0.z); v[3] = (short)f2bf(f0.w);
        v[4] = (short)f2bf(f1.x); v[5] = (short)f2bf(f1.y); v[6] = (short)f2bf(f1.z); v[7] = (short)f2bf(f1.w);
        int kk = p * 16 + o * 8;
        *(short8v*)(Ab + t * 256 + ((kk * 2) ^ ((t & 7) << 4))) = v;
      }
    }
    __syncthreads();
    short8v a[4];
#pragma unroll
    for (int ks = 0; ks < 4; ++ks)
      a[ks] = *(const short8v*)(Ab + (16 * w + lr) * 256 + ((ks * 64 + lgp * 16) ^ ((lr & 7) << 4)));
#pragma unroll
    for (int nt = 0; nt < 8; ++nt) {
#pragma unroll
      for (int ks = 0; ks < 4; ++ks) {
        short8v b = *(const short8v*)(Bb + (nt * 16 + lr) * 256 + ((ks * 64 + lgp * 16) ^ ((lr & 7) << 4)));
        acc[nt] = __builtin_amdgcn_mfma_f32_16x16x32_bf16(a[ks], b, acc[nt], 0, 0, 0);
      }
    }
  }
  // fused pos layernorm over the 128 outputs of each token row
  float s4[4] = {0,0,0,0}, q4[4] = {0,0,0,0};
#pragma unroll
  for (int nt = 0; nt < 8; ++nt) {
    const float bb = spb[nt * 16 + lr];
#pragma unroll
    for (int r = 0; r < 4; ++r) { float v = acc[nt][r] + bb; s4[r] += v; q4[r] += v * v; }
  }
#pragma unroll
  for (int r = 0; r < 4; ++r) {
    for (int off = 1; off < 16; off <<= 1) {
      s4[r] += __shfl_xor(s4[r], off, 16);
      q4[r] += __shfl_xor(q4[r], off, 16);
    }
  }
#pragma unroll
  for (int r = 0; r < 4; ++r) {
    float mean = s4[r] * (1.f / 128.f);
    float var  = q4[r] * (1.f / 128.f) - mean * mean;
    float rstd = rsqrtf(var + EPS);
    const size_t row = (size_t)(m0 + 16 * w + lgp * 4 + r) * 128;
#pragma unroll
    for (int nt = 0; nt < 8; ++nt) {
      int col = nt * 16 + lr;
      float v = acc[nt][r] + spb[col];
      tok[row + col] = (v - mean) * rstd * spg[col] + spe[col];
    }
  }
}

// ---------------- fused layernorm + in_proj (MFMA) ----------------
// grid 1024 = 256 m-blocks x 4 n-blocks; 256 threads
__global__ __launch_bounds__(256) void k_inproj(const float* __restrict__ tok,
    const ushort_t* __restrict__ inwb, const float* __restrict__ biasin,
    float* __restrict__ zx){
  __shared__ ushort_t Al[64 * 128];
  __shared__ ushort_t Bl[176 * 128];
  __shared__ float sBias[176];
  const int blk = blockIdx.x;
  const int mb = blk >> 2, nb = blk & 3;
  const int m0 = mb * 64, n0 = nb * 176;
  const int NT = (nb == 3) ? 128 : 176;
  const int tid = threadIdx.x;
  char* Ab = (char*)Al; char* Bb = (char*)Bl;
  for (int idx = tid; idx < (NT << 4); idx += 256) {
    int row = idx >> 4, ch = idx & 15;
    short8v v = *(const short8v*)(inwb + ((size_t)(n0 + row) << 7) + (ch << 3));
    *(short8v*)(Bb + row * 256 + ((ch * 16) ^ ((row & 7) << 4))) = v;
  }
  for (int idx = tid; idx < NT; idx += 256) sBias[idx] = biasin[n0 + idx];
  // stage A: LN (affine folded into weights) -> bf16, swizzled
  {
    const int r = tid >> 2, t4 = tid & 3;
    const float* src = tok + (((size_t)(m0 + r)) << 7) + t4 * 32;
    float v[32];
    float s = 0.f, sq = 0.f;
#pragma unroll
    for (int k = 0; k < 8; ++k) {
      float4 f = *(const float4*)(src + 4 * k);
      v[4*k] = f.x; v[4*k+1] = f.y; v[4*k+2] = f.z; v[4*k+3] = f.w;
      s += f.x + f.y + f.z + f.w;
      sq += f.x*f.x + f.y*f.y + f.z*f.z + f.w*f.w;
    }
    s  += __shfl_xor(s, 1, 4);  s  += __shfl_xor(s, 2, 4);
    sq += __shfl_xor(sq, 1, 4); sq += __shfl_xor(sq, 2, 4);
    float mean = s * (1.f / 128.f);
    float var  = sq * (1.f / 128.f) - mean * mean;
    float rstd = rsqrtf(var + EPS);
#pragma unroll
    for (int k = 0; k < 4; ++k) {
      short8v o;
#pragma unroll
      for (int e = 0; e < 8; ++e) o[e] = (short)f2bf((v[8*k + e] - mean) * rstd);
      *(short8v*)(Ab + r * 256 + ((t4 * 64 + 16 * k) ^ ((r & 7) << 4))) = o;
    }
  }
  __syncthreads();
  const int w = tid >> 6, l = tid & 63, lr = l & 15, lgp = l >> 4;
  short8v a[4];
#pragma unroll
  for (int ks = 0; ks < 4; ++ks)
    a[ks] = *(const short8v*)(Ab + (16 * w + lr) * 256 + ((ks * 64 + lgp * 16) ^ ((lr & 7) << 4)));
  const int NTT = NT >> 4;
  for (int nt = 0; nt < NTT; ++nt) {
    f32x4 acc = (f32x4){0.f, 0.f, 0.f, 0.f};
#pragma unroll
    for (int ks = 0; ks < 4; ++ks) {
      short8v b = *(const short8v*)(Bb + (nt * 16 + lr) * 256 + ((ks * 64 + lgp * 16) ^ ((lr & 7) << 4)));
      acc = __builtin_amdgcn_mfma_f32_16x16x32_bf16(a[ks], b, acc, 0, 0, 0);
    }
    const int col = n0 + nt * 16 + lr;
    if (col < DPROJ) {
      const float bias = sBias[nt * 16 + lr];
#pragma unroll
      for (int r = 0; r < 4; ++r)
        zx[((size_t)(m0 + 16 * w + lgp * 4 + r)) * DPROJ + col] = acc[r] + bias;
    }
  }
}

// ---------------- causal depthwise conv + silu ----------------
__global__ __launch_bounds__(384) void k_conv(const float* __restrict__ zx,
    const float* __restrict__ cw, const float* __restrict__ cb, float* __restrict__ xc){
  const int b = blockIdx.x >> 10, l = blockIdx.x & 1023, ch = threadIdx.x;
  float acc = cb[ch];
  const float w0 = cw[ch * 4], w1 = cw[ch * 4 + 1], w2 = cw[ch * 4 + 2], w3 = cw[ch * 4 + 3];
  const float* base = zx + ((size_t)(b << 10)) * DPROJ + DI + ch;
  if (l >= 3) acc += base[(size_t)(l - 3) * DPROJ] * w0;
  if (l >= 2) acc += base[(size_t)(l - 2) * DPROJ] * w1;
  if (l >= 1) acc += base[(size_t)(l - 1) * DPROJ] * w2;
  acc += base[(size_t)l * DPROJ] * w3;
  acc = silu_f(acc);
  xc[((size_t)(b << 10) + l) * CDIM + ch] = acc;
}

// ---------------- SSD step 1: dt + within-chunk cumulative log-decay ----------------
__global__ __launch_bounds__(64) void k_dt(const float* __restrict__ zx,
    const float* __restrict__ dtbias, const float* __restrict__ Alog,
    float* __restrict__ dtb, float* __restrict__ lcb, float* __restrict__ Acb){
  const int blk = blockIdx.x;
  const int c = blk & 15, h = (blk >> 4) & 7, b = blk >> 7;
  const int s = threadIdx.x;
  const int l = (c << 6) + s;
  float raw = zx[((size_t)(b << 10) + l) * DPROJ + 640 + h] + dtbias[h];
  float dt = raw > 20.f ? raw : log1pf(expf(raw));
  float la = dt * (-expf(Alog[h]));
  float cum = la;
  for (int off = 1; off < 64; off <<= 1) {
    float v = __shfl_up(cum, off, 64);
    if (s >= off) cum += v;
  }
  size_t o = ((size_t)((b << 3) + h) << 10) + l;
  dtb[o] = dt; lcb[o] = cum;
  if (s == 63) Acb[blk] = expf(cum);
}

// ---------------- SSD step 2: per-chunk state S_c ----------------
__global__ __launch_bounds__(256) void k_cstate(const float* __restrict__ xc,
    const float* __restrict__ dtb, const float* __restrict__ lcb,
    float* __restrict__ Sc){
  __shared__ float sB[64][64];
  __shared__ float sX[64][32];
  __shared__ float scoef[64];
  const int blk = blockIdx.x;
  const int c = blk & 15, h = (blk >> 4) & 7, b = blk >> 7;
  const int tid = threadIdx.x;
  const int l0 = c << 6;
  for (int i = tid; i < 64 * 16; i += 256) {
    int r = i >> 4, q = i & 15;
    float4 v = *(const float4*)(xc + ((size_t)(b << 10) + l0 + r) * CDIM + DI + q * 4);
    *(float4*)(&sB[r][q * 4]) = v;
  }
  for (int i = tid; i < 64 * 8; i += 256) {
    int r = i >> 3, q = i & 7;
    float4 v = *(const float4*)(xc + ((size_t)(b << 10) + l0 + r) * CDIM + (h << 5) + q * 4);
    *(float4*)(&sX[r][q * 4]) = v;
  }
  if (tid < 64) {
    size_t o = ((size_t)((b << 3) + h) << 10) + l0;
    float lcT = lcb[o + 63];
    scoef[tid] = dtb[o + tid] * __expf(lcT - lcb[o + tid]);
  }
  __syncthreads();
  const int p = tid >> 3, n8 = (tid & 7) << 3;
  float S[8] = {0,0,0,0,0,0,0,0};
  for (int s = 0; s < 64; ++s) {
    const float cf = scoef[s] * sX[s][p];
#pragma unroll
    for (int j = 0; j < 8; ++j) S[j] += cf * sB[s][n8 + j];
  }
  float* dst = Sc + ((size_t)blk << 11) + (p << 6) + n8;
  *(float4*)dst       = make_float4(S[0], S[1], S[2], S[3]);
  *(float4*)(dst + 4) = make_float4(S[4], S[5], S[6], S[7]);
}

// ---------------- SSD step 3: inter-chunk scan ----------------
__global__ __launch_bounds__(256) void k_hscan(float* __restrict__ Sc, const float* __restrict__ Acb){
  const int blk = blockIdx.x;
  const int bh = blk >> 3;
  const int e = ((blk & 7) << 8) + threadIdx.x;
  float hs = 0.f;
  const size_t base = ((size_t)bh << 15) + e;
  for (int c = 0; c < 16; ++c) {
    const size_t o = base + ((size_t)c << 11);
    float v = Sc[o];
    Sc[o] = hs;
    hs = Acb[(bh << 4) + c] * hs + v;
  }
}

// ---------------- SSD step 4: within-chunk outputs (G deduped via LDS) ----------------
__global__ __launch_bounds__(256) void k_chunky(const float* __restrict__ xc,
    const float* __restrict__ h0buf, const float* __restrict__ dtb,
    const float* __restrict__ lcb, const float* __restrict__ Dsk,
    float* __restrict__ ys){
  __shared__ float sC[64][65];
  __shared__ float sB[64][64];   // reused as sW[s][t] after phase A
  __shared__ float sX[64][33];
  __shared__ float sH[32][64];
  __shared__ float sdt[64], slc[64];
  const int blk = blockIdx.x;
  const int c = blk & 15, h = (blk >> 4) & 7, b = blk >> 7;
  const int tid = threadIdx.x;
  const int l0 = c << 6;
  for (int i = tid; i < 64 * 16; i += 256) {
    int r = i >> 4, q = i & 15;
    size_t rowb = ((size_t)(b << 10) + l0 + r) * CDIM;
    float4 vb = *(const float4*)(xc + rowb + DI + q * 4);
    float4 vc = *(const float4*)(xc + rowb + DI + DS + q * 4);
    *(float4*)(&sB[r][q * 4]) = vb;
    sC[r][q * 4] = vc.x; sC[r][q * 4 + 1] = vc.y; sC[r][q * 4 + 2] = vc.z; sC[r][q * 4 + 3] = vc.w;
  }
  for (int i = tid; i < 64 * 8; i += 256) {
    int r = i >> 3, q = i & 7;
    float4 v = *(const float4*)(xc + ((size_t)(b << 10) + l0 + r) * CDIM + (h << 5) + q * 4);
    sX[r][q * 4] = v.x; sX[r][q * 4 + 1] = v.y; sX[r][q * 4 + 2] = v.z; sX[r][q * 4 + 3] = v.w;
  }
  for (int i = tid; i < 512; i += 256) {
    float4 v = *(const float4*)(h0buf + ((size_t)blk << 11) + i * 4);
    *(float4*)(&sH[0][0] + i * 4) = v;
  }
  if (tid < 64) {
    size_t o = ((size_t)((b << 3) + h) << 10) + l0;
    sdt[tid] = dtb[o + tid];
    slc[tid] = lcb[o + tid];
  }
  __syncthreads();
  const int t = tid & 63, sg = tid >> 6;
  float Creg[64];
#pragma unroll
  for (int n = 0; n < 64; ++n) Creg[n] = sC[t][n];
  const float lct = slc[t];
  // phase A: each wave computes 16 rows of the masked weight matrix W[t][s]
  float W[16];
#pragma unroll
  for (int j = 0; j < 16; ++j) {
    const int s = sg * 16 + j;
    float g = 0.f;
#pragma unroll
    for (int n = 0; n < 64; ++n) g += Creg[n] * sB[s][n];
    W[j] = (s <= t) ? sdt[s] * __expf(fminf(lct - slc[s], 0.f)) * g : 0.f;
  }
  __syncthreads();
#pragma unroll
  for (int j = 0; j < 16; ++j) sB[sg * 16 + j][t] = W[j];
  // overlap: h0 contribution while sW settles
  const float Pt = __expf(lct);
  const int pg = sg << 3;
  float y[8];
#pragma unroll
  for (int jj = 0; jj < 8; ++jj) {
    float a = 0.f;
#pragma unroll
    for (int n = 0; n < 64; ++n) a += sH[pg + jj][n] * Creg[n];
    y[jj] = Pt * a;
  }
  __syncthreads();
  for (int s = 0; s < 64; ++s) {
    const float ww = sB[s][t];
#pragma unroll
    for (int jj = 0; jj < 8; ++jj) y[jj] += ww * sX[s][pg + jj];
  }
  const float dsk = Dsk[h];
  float* dst = ys + ((size_t)(b << 10) + l0 + t) * DI + (h << 5) + pg;
#pragma unroll
  for (int j = 0; j < 8; ++j) dst[j] = y[j] + dsk * sX[t][pg + j];
}

// ---------------- gate*silu(z), RMSNorm, out_proj (MFMA), residual add ----------------
// grid 256 (64 tokens/block), 256 threads; nw folded into owb
__global__ __launch_bounds__(256) void k_gateout(const float* __restrict__ zx,
    const float* __restrict__ ys, const ushort_t* __restrict__ owb,
    float* __restrict__ tok){
  __shared__ ushort_t Al[64 * 256];
  __shared__ ushort_t Bl[128 * 64];
  const int m0 = blockIdx.x * 64;
  const int tid = threadIdx.x;
  char* Ab = (char*)Al; char* Bb = (char*)Bl;
  // stage A: gate + RMSNorm -> bf16
  {
    const int r = tid >> 2, t4 = tid & 3;
    const size_t row = (size_t)(m0 + r);
    const float* yp = ys + row * 256 + t4 * 64;
    const float* zp = zx + row * DPROJ + t4 * 64;
    float p[64];
    float sq = 0.f;
#pragma unroll
    for (int k = 0; k < 16; ++k) {
      float4 fy = *(const float4*)(yp + 4 * k);
      float4 fz = *(const float4*)(zp + 4 * k);
      float a0 = fy.x * (fz.x / (1.f + __expf(-fz.x)));
      float a1 = fy.y * (fz.y / (1.f + __expf(-fz.y)));
      float a2 = fy.z * (fz.z / (1.f + __expf(-fz.z)));
      float a3 = fy.w * (fz.w / (1.f + __expf(-fz.w)));
      p[4*k] = a0; p[4*k+1] = a1; p[4*k+2] = a2; p[4*k+3] = a3;
      sq += a0*a0 + a1*a1 + a2*a2 + a3*a3;
    }
    sq += __shfl_xor(sq, 1, 4); sq += __shfl_xor(sq, 2, 4);
    float rstd = rsqrtf(sq * (1.f / 256.f) + EPS);
#pragma unroll
    for (int k = 0; k < 8; ++k) {
      short8v o;
#pragma unroll
      for (int e = 0; e < 8; ++e) o[e] = (short)f2bf(p[8*k + e] * rstd);
      *(short8v*)(Ab + r * 512 + ((t4 * 128 + 16 * k) ^ ((r & 7) << 4))) = o;
    }
  }
  const int w = tid >> 6, l = tid & 63, lr = l & 15, lgp = l >> 4;
  f32x4 acc[8];
#pragma unroll
  for (int nt = 0; nt < 8; ++nt) acc[nt] = (f32x4){0.f, 0.f, 0.f, 0.f};
  for (int kq = 0; kq < 4; ++kq) {
    __syncthreads();   // kq=0: also covers A staging
    for (int idx = tid; idx < 128 * 8; idx += 256) {
      int row = idx >> 3, ch = idx & 7;
      short8v v = *(const short8v*)(owb + ((size_t)row << 8) + kq * 64 + (ch << 3));
      *(short8v*)(Bb + row * 128 + ((ch * 16) ^ ((row & 7) << 4))) = v;
    }
    __syncthreads();
    short8v a0 = *(const short8v*)(Ab + (16*w + lr) * 512 + ((kq * 128 +      lgp * 16) ^ ((lr & 7) << 4)));
    short8v a1 = *(const short8v*)(Ab + (16*w + lr) * 512 + ((kq * 128 + 64 + lgp * 16) ^ ((lr & 7) << 4)));
#pragma unroll
    for (int nt = 0; nt < 8; ++nt) {
      short8v b0 = *(const short8v*)(Bb + (nt * 16 + lr) * 128 + ((     lgp * 16) ^ ((lr & 7) << 4)));
      short8v b1 = *(const short8v*)(Bb + (nt * 16 + lr) * 128 + ((64 + lgp * 16) ^ ((lr & 7) << 4)));
      acc[nt] = __builtin_amdgcn_mfma_f32_16x16x32_bf16(a0, b0, acc[nt], 0, 0, 0);
      acc[nt] = __builtin_amdgcn_mfma_f32_16x16x32_bf16(a1, b1, acc[nt], 0, 0, 0);
    }
  }
#pragma unroll
  for (int nt = 0; nt < 8; ++nt) {
#pragma unroll
    for (int r = 0; r < 4; ++r) {
      tok[((size_t)(m0 + 16 * w + lgp * 4 + r)) * 128 + nt * 16 + lr] += acc[nt][r];
    }
  }
}

// ---------------- final LN + attention scores ----------------
__global__ __launch_bounds__(128) void k_score(const float* __restrict__ tok,
    const float* __restrict__ fg, const float* __restrict__ fb,
    const float* __restrict__ w1, const float* __restrict__ b1,
    const float* __restrict__ w2, const float* __restrict__ b2,
    float* __restrict__ tokF, float* __restrict__ sc){
  __shared__ float st[8][128];
  __shared__ float sh[8][64];
  const int blk = blockIdx.x, b = blk >> 7, tg = (blk & 127) << 3, tid = threadIdx.x;
  for (int i = tid; i < 1024; i += 128) {
    int j = i >> 7, d = i & 127;
    st[j][d] = tok[((size_t)(b << 10) + tg + j) * DM + d];
  }
  __syncthreads();
  {
    const int j = tid >> 4, ln = tid & 15;
    float v[8]; float s = 0, sq = 0;
#pragma unroll
    for (int k = 0; k < 8; ++k) { v[k] = st[j][ln + (k << 4)]; s += v[k]; sq += v[k] * v[k]; }
    for (int off = 8; off; off >>= 1) { s += __shfl_xor(s, off, 16); sq += __shfl_xor(sq, off, 16); }
    float mean = s * (1.f / 128.f), var = sq * (1.f / 128.f) - mean * mean;
    float rstd = rsqrtf(var + EPS);
#pragma unroll
    for (int k = 0; k < 8; ++k) {
      int d = ln + (k << 4);
      float o = (v[k] - mean) * rstd * fg[d] + fb[d];
      st[j][d] = o;
      tokF[((size_t)(b << 10) + tg + j) * DM + d] = o;
    }
  }
  __syncthreads();
  {
    const int hh = tid & 63, jh = tid >> 6;
    const float* row = w1 + (size_t)hh * DM;
    const float bb = b1[hh];
    for (int jj = jh; jj < 8; jj += 2) {
      float a = bb;
      for (int d = 0; d < DM; ++d) a += row[d] * st[jj][d];
      sh[jj][hh] = tanhf(a);
    }
  }
  __syncthreads();
  if (tid < 8) {
    float a = b2[0];
    for (int k = 0; k < 64; ++k) a += sh[tid][k] * w2[k];
    sc[(size_t)(b << 10) + tg + tid] = a;
  }
}

// ---------------- softmax pool + l2 normalize ----------------
__global__ __launch_bounds__(256) void k_pool(const float* __restrict__ tokF,
    const float* __restrict__ sc, float* __restrict__ out){
  __shared__ float sw[1024];
  __shared__ float sred[4];
  __shared__ float sp[2][128];
  const int b = blockIdx.x, tid = threadIdx.x, wv = tid >> 6, ln = tid & 63;
  const float* s = sc + ((size_t)b << 10);
  float mx = -1e30f;
  for (int l = tid; l < 1024; l += 256) mx = fmaxf(mx, s[l]);
  for (int off = 32; off; off >>= 1) mx = fmaxf(mx, __shfl_xor(mx, off));
  if (ln == 0) sred[wv] = mx;
  __syncthreads();
  mx = fmaxf(fmaxf(sred[0], sred[1]), fmaxf(sred[2], sred[3]));
  float se = 0;
  for (int l = tid; l < 1024; l += 256) { float e = expf(s[l] - mx); sw[l] = e; se += e; }
  for (int off = 32; off; off >>= 1) se += __shfl_xor(se, off);
  __syncthreads();
  if (ln == 0) sred[wv] = se;
  __syncthreads();
  se = sred[0] + sred[1] + sred[2] + sred[3];
  const float inv = 1.f / se;
  const int d = tid & 127, hf = tid >> 7;
  float acc = 0;
  const float* tf = tokF + ((size_t)b << 10) * DM;
  for (int l = hf * 512; l < (hf + 1) * 512; ++l) acc += sw[l] * tf[(size_t)l * DM + d];
  sp[hf][d] = acc;
  __syncthreads();
  if (tid < 128) sp[0][tid] = (sp[0][tid] + sp[1][tid]) * inv;
  __syncthreads();
  if (tid < 64) {
    float v0 = sp[0][tid], v1 = sp[0][tid + 64];
    float sq = v0 * v0 + v1 * v1;
    for (int off = 32; off; off >>= 1) sq += __shfl_xor(sq, off);
    float nrm = fmaxf(sqrtf(sq), 1e-12f);
    out[(size_t)b * DM + tid]      = v0 / nrm;
    out[(size_t)b * DM + tid + 64] = v1 / nrm;
  }
}

extern "C" void kernel_launch(void* const* d_in, const int* in_sizes, int n_in,
                              void* d_out, int out_size, void* d_ws, size_t ws_size,
                              hipStream_t stream) {
  const float* x       = (const float*)d_in[0];
  const float* patch_w = (const float*)d_in[1];
  const float* patch_b = (const float*)d_in[2];
  const float* pe_g    = (const float*)d_in[3];
  const float* pe_b    = (const float*)d_in[4];
  const float* in_w    = (const float*)d_in[5];
  const float* conv_w  = (const float*)d_in[6];
  const float* conv_b  = (const float*)d_in[7];
  const float* dt_bias = (const float*)d_in[8];
  const float* A_log   = (const float*)d_in[9];
  const float* D_skip  = (const float*)d_in[10];
  const float* nw      = (const float*)d_in[11];
  const float* out_w   = (const float*)d_in[12];
  const float* ln_g    = (const float*)d_in[13];
  const float* ln_b    = (const float*)d_in[14];
  const float* fn_g    = (const float*)d_in[15];
  const float* fn_b    = (const float*)d_in[16];
  const float* w1      = (const float*)d_in[17];
  const float* b1      = (const float*)d_in[18];
  const float* w2      = (const float*)d_in[19];
  const float* b2      = (const float*)d_in[20];
  float* out = (float*)d_out;
  char* ws = (char*)d_ws;

  size_t off = 0;
  float* tok  = (float*)(ws + off); off += (size_t)NB * L * DM * 4;
  float* zx   = (float*)(ws + off); off += (size_t)NB * L * DPROJ * 4;
  float* xcb  = (float*)(ws + off); off += (size_t)NB * L * CDIM * 4;
  float* ysb  = (float*)(ws + off); off += (size_t)NB * L * DI * 4;
  float* Scb  = (float*)(ws + off); off += (size_t)NB * NH * 16 * 2048 * 4;
  float* dtb  = (float*)(ws + off); off += (size_t)NB * NH * L * 4;
  float* lcb  = (float*)(ws + off); off += (size_t)NB * NH * L * 4;
  float* Acb  = (float*)(ws + off); off += (size_t)NB * NH * 16 * 4;
  ushort_t* inwb = (ushort_t*)(ws + off); off += (size_t)4 * EPAD * 128 * 2;
  ushort_t* owb  = (ushort_t*)(ws + off); off += (size_t)4 * 128 * 256 * 2;
  ushort_t* pwb  = (ushort_t*)(ws + off); off += (size_t)128 * 768 * 2;
  float* biasin  = (float*)(ws + off); off += (size_t)4 * EPAD * 4;
  float* tokF = zx;                                            // zx dead after layers
  float* scb  = (float*)(ws + (size_t)30 * 1024 * 1024);       // inside zx, past tokF

  {
    const int total = 4 * EPAD * 128 + 4 * 128 * 256 + 128 * 768 + 4 * EPAD;
    k_cvt<<<(total + 255) / 256, 256, 0, stream>>>(in_w, ln_g, ln_b, out_w, nw, patch_w,
                                                   inwb, owb, pwb, biasin);
  }
  k_patch<<<256, 256, 0, stream>>>(x, pwb, patch_b, pe_g, pe_b, tok);
  for (int ly = 0; ly < 4; ++ly) {
    k_inproj<<<1024, 256, 0, stream>>>(tok, inwb + (size_t)ly * EPAD * 128,
                                       biasin + ly * EPAD, zx);
    k_conv<<<NB * L, CDIM, 0, stream>>>(zx, conv_w + (size_t)ly * CDIM * 4,
                                        conv_b + ly * CDIM, xcb);
    k_dt<<<NB * NH * 16, 64, 0, stream>>>(zx, dt_bias + ly * NH, A_log + ly * NH,
                                          dtb, lcb, Acb);
    k_cstate<<<NB * NH * 16, 256, 0, stream>>>(xcb, dtb, lcb, Scb);
    k_hscan<<<NB * NH * 8, 256, 0, stream>>>(Scb, Acb);
    k_chunky<<<NB * NH * 16, 256, 0, stream>>>(xcb, Scb, dtb, lcb,
                                               D_skip + ly * NH, ysb);
    k_gateout<<<256, 256, 0, stream>>>(zx, ysb, owb + (size_t)ly * 128 * 256, tok);
  }
  k_score<<<2048, 128, 0, stream>>>(tok, fn_g, fn_b, w1, b1, w2, b2, tokF, scb);
  k_pool<<<16, 256, 0, stream>>>(tokF, scb, out);
}

// Round 4
// 589.795 us; speedup vs baseline: 4.6139x; 1.4660x over previous
//
#include <hip/hip_runtime.h>
#include <math.h>

#define EPS 1e-5f

constexpr int NB      = 16;
constexpr int L       = 1024;
constexpr int DM      = 128;
constexpr int DI      = 256;
constexpr int DS      = 64;
constexpr int NH      = 8;
constexpr int DPROJ   = 648;   // 2*DI + 2*DS + NH
constexpr int CDIM    = 384;   // DI + 2*DS
constexpr int EPAD    = 656;   // DPROJ padded to 41*16

typedef __attribute__((ext_vector_type(8))) short short8v;
typedef __attribute__((ext_vector_type(4))) float f32x4;
typedef unsigned short ushort_t;

__device__ __forceinline__ float silu_f(float x){ return x / (1.f + expf(-x)); }
__device__ __forceinline__ ushort_t f2bf(float f){
  union { float f; unsigned int u; } v; v.f = f;
  unsigned int r = v.u + 0x7FFF + ((v.u >> 16) & 1);
  return (ushort_t)(r >> 16);
}
__device__ __forceinline__ short8v pack8(float4 a, float4 b){
  short8v v;
  v[0]=(short)f2bf(a.x); v[1]=(short)f2bf(a.y); v[2]=(short)f2bf(a.z); v[3]=(short)f2bf(a.w);
  v[4]=(short)f2bf(b.x); v[5]=(short)f2bf(b.y); v[6]=(short)f2bf(b.z); v[7]=(short)f2bf(b.w);
  return v;
}

// ---------------- weight conversion / folding (runs once per launch) ----------------
__global__ __launch_bounds__(256) void k_cvt(const float* __restrict__ in_w,
    const float* __restrict__ ln_g, const float* __restrict__ ln_b,
    const float* __restrict__ out_w, const float* __restrict__ nw,
    const float* __restrict__ patch_w,
    ushort_t* __restrict__ inwb, ushort_t* __restrict__ owb,
    ushort_t* __restrict__ pwb, float* __restrict__ biasin){
  const int R1 = 4 * EPAD * 128, R2 = 4 * 128 * 256, R3 = 128 * 768, R4 = 4 * EPAD;
  int i = blockIdx.x * 256 + threadIdx.x;
  if (i < R1) {
    int ly = i / (EPAD * 128), rem = i % (EPAD * 128), e = rem >> 7, d = rem & 127;
    float v = 0.f;
    if (e < DPROJ) v = in_w[((size_t)ly * DPROJ + e) * 128 + d] * ln_g[ly * 128 + d];
    inwb[i] = f2bf(v);
    return;
  }
  i -= R1;
  if (i < R2) {
    int ly = i >> 15, rem = i & 32767, e = rem & 255;
    owb[i] = f2bf(out_w[i] * nw[ly * 256 + e]);
    return;
  }
  i -= R2;
  if (i < R3) { pwb[i] = f2bf(patch_w[i]); return; }
  i -= R3;
  if (i < R4) {
    int ly = i / EPAD, e = i % EPAD;
    float s = 0.f;
    if (e < DPROJ) {
      const float* r = in_w + ((size_t)ly * DPROJ + e) * 128;
      const float* b = ln_b + ly * 128;
      for (int d = 0; d < 128; ++d) s += r[d] * b[d];
    }
    biasin[i] = s;
  }
}

// ---------------- patch embed (MFMA) + pos layernorm ----------------
__global__ __launch_bounds__(256) void k_patch(const float* __restrict__ x,
    const ushort_t* __restrict__ pwb, const float* __restrict__ pb,
    const float* __restrict__ pg, const float* __restrict__ pbe,
    float* __restrict__ tok){
  __shared__ ushort_t Al[64 * 128];
  __shared__ ushort_t Bl[128 * 128];
  __shared__ float spb[128], spg[128], spe[128];
  const int m0 = blockIdx.x * 64;
  const int tid = threadIdx.x;
  char* Ab = (char*)Al; char* Bb = (char*)Bl;
  if (tid < 128) { spb[tid] = pb[tid]; spg[tid] = pg[tid]; spe[tid] = pbe[tid]; }
  const int w = tid >> 6, l = tid & 63, lr = l & 15, lgp = l >> 4;
  f32x4 acc[8];
#pragma unroll
  for (int nt = 0; nt < 8; ++nt) acc[nt] = (f32x4){0.f, 0.f, 0.f, 0.f};
  for (int kc = 0; kc < 6; ++kc) {
    __syncthreads();
    for (int idx = tid; idx < 128 * 16; idx += 256) {
      int n = idx >> 4, ch = idx & 15;
      short8v v = *(const short8v*)(pwb + (size_t)n * 768 + kc * 128 + (ch << 3));
      *(short8v*)(Bb + n * 256 + ((ch * 16) ^ ((n & 7) << 4))) = v;
    }
    {
      const int c = kc >> 1;
      for (int i = tid; i < 1024; i += 256) {
        int t = i >> 4, p = (i >> 1) & 7, o = i & 1;
        int T = m0 + t, bb = T >> 10, tl = T & 1023, hp = tl >> 5, wp = tl & 31;
        const float* src = x + (((size_t)(bb * 3 + c) * 512 + hp * 16 + ((kc & 1) << 3) + p) * 512
                                + wp * 16 + o * 8);
        float4 f0 = *(const float4*)src;
        float4 f1 = *(const float4*)(src + 4);
        short8v v = pack8(f0, f1);
        int kk = p * 16 + o * 8;
        *(short8v*)(Ab + t * 256 + ((kk * 2) ^ ((t & 7) << 4))) = v;
      }
    }
    __syncthreads();
    short8v a[4];
#pragma unroll
    for (int ks = 0; ks < 4; ++ks)
      a[ks] = *(const short8v*)(Ab + (16 * w + lr) * 256 + ((ks * 64 + lgp * 16) ^ ((lr & 7) << 4)));
#pragma unroll
    for (int nt = 0; nt < 8; ++nt) {
#pragma unroll
      for (int ks = 0; ks < 4; ++ks) {
        short8v b = *(const short8v*)(Bb + (nt * 16 + lr) * 256 + ((ks * 64 + lgp * 16) ^ ((lr & 7) << 4)));
        acc[nt] = __builtin_amdgcn_mfma_f32_16x16x32_bf16(a[ks], b, acc[nt], 0, 0, 0);
      }
    }
  }
  float s4[4] = {0,0,0,0}, q4[4] = {0,0,0,0};
#pragma unroll
  for (int nt = 0; nt < 8; ++nt) {
    const float bb = spb[nt * 16 + lr];
#pragma unroll
    for (int r = 0; r < 4; ++r) { float v = acc[nt][r] + bb; s4[r] += v; q4[r] += v * v; }
  }
#pragma unroll
  for (int r = 0; r < 4; ++r) {
    for (int off = 1; off < 16; off <<= 1) {
      s4[r] += __shfl_xor(s4[r], off, 16);
      q4[r] += __shfl_xor(q4[r], off, 16);
    }
  }
#pragma unroll
  for (int r = 0; r < 4; ++r) {
    float mean = s4[r] * (1.f / 128.f);
    float var  = q4[r] * (1.f / 128.f) - mean * mean;
    float rstd = rsqrtf(var + EPS);
    const size_t row = (size_t)(m0 + 16 * w + lgp * 4 + r) * 128;
#pragma unroll
    for (int nt = 0; nt < 8; ++nt) {
      int col = nt * 16 + lr;
      float v = acc[nt][r] + spb[col];
      tok[row + col] = (v - mean) * rstd * spg[col] + spe[col];
    }
  }
}

// ---------------- fused layernorm + in_proj (MFMA) ----------------
__global__ __launch_bounds__(256) void k_inproj(const float* __restrict__ tok,
    const ushort_t* __restrict__ inwb, const float* __restrict__ biasin,
    float* __restrict__ zx){
  __shared__ ushort_t Al[64 * 128];
  __shared__ ushort_t Bl[176 * 128];
  __shared__ float sBias[176];
  const int blk = blockIdx.x;
  const int mb = blk >> 2, nb = blk & 3;
  const int m0 = mb * 64, n0 = nb * 176;
  const int NT = (nb == 3) ? 128 : 176;
  const int tid = threadIdx.x;
  char* Ab = (char*)Al; char* Bb = (char*)Bl;
  for (int idx = tid; idx < (NT << 4); idx += 256) {
    int row = idx >> 4, ch = idx & 15;
    short8v v = *(const short8v*)(inwb + ((size_t)(n0 + row) << 7) + (ch << 3));
    *(short8v*)(Bb + row * 256 + ((ch * 16) ^ ((row & 7) << 4))) = v;
  }
  for (int idx = tid; idx < NT; idx += 256) sBias[idx] = biasin[n0 + idx];
  {
    const int r = tid >> 2, t4 = tid & 3;
    const float* src = tok + (((size_t)(m0 + r)) << 7) + t4 * 32;
    float v[32];
    float s = 0.f, sq = 0.f;
#pragma unroll
    for (int k = 0; k < 8; ++k) {
      float4 f = *(const float4*)(src + 4 * k);
      v[4*k] = f.x; v[4*k+1] = f.y; v[4*k+2] = f.z; v[4*k+3] = f.w;
      s += f.x + f.y + f.z + f.w;
      sq += f.x*f.x + f.y*f.y + f.z*f.z + f.w*f.w;
    }
    s  += __shfl_xor(s, 1, 4);  s  += __shfl_xor(s, 2, 4);
    sq += __shfl_xor(sq, 1, 4); sq += __shfl_xor(sq, 2, 4);
    float mean = s * (1.f / 128.f);
    float var  = sq * (1.f / 128.f) - mean * mean;
    float rstd = rsqrtf(var + EPS);
#pragma unroll
    for (int k = 0; k < 4; ++k) {
      short8v o;
#pragma unroll
      for (int e = 0; e < 8; ++e) o[e] = (short)f2bf((v[8*k + e] - mean) * rstd);
      *(short8v*)(Ab + r * 256 + ((t4 * 64 + 16 * k) ^ ((r & 7) << 4))) = o;
    }
  }
  __syncthreads();
  const int w = tid >> 6, l = tid & 63, lr = l & 15, lgp = l >> 4;
  short8v a[4];
#pragma unroll
  for (int ks = 0; ks < 4; ++ks)
    a[ks] = *(const short8v*)(Ab + (16 * w + lr) * 256 + ((ks * 64 + lgp * 16) ^ ((lr & 7) << 4)));
  const int NTT = NT >> 4;
  for (int nt = 0; nt < NTT; ++nt) {
    f32x4 acc = (f32x4){0.f, 0.f, 0.f, 0.f};
#pragma unroll
    for (int ks = 0; ks < 4; ++ks) {
      short8v b = *(const short8v*)(Bb + (nt * 16 + lr) * 256 + ((ks * 64 + lgp * 16) ^ ((lr & 7) << 4)));
      acc = __builtin_amdgcn_mfma_f32_16x16x32_bf16(a[ks], b, acc, 0, 0, 0);
    }
    const int col = n0 + nt * 16 + lr;
    if (col < DPROJ) {
      const float bias = sBias[nt * 16 + lr];
#pragma unroll
      for (int r = 0; r < 4; ++r)
        zx[((size_t)(m0 + 16 * w + lgp * 4 + r)) * DPROJ + col] = acc[r] + bias;
    }
  }
}

// ---------------- causal depthwise conv + silu (LDS-tiled) ----------------
// grid NB*16*2 = 512; 256 threads; 64 tokens x 192 channels per block
constexpr int CONVC = 192;
__global__ __launch_bounds__(256) void k_conv(const float* __restrict__ zx,
    const float* __restrict__ cw, const float* __restrict__ cb, float* __restrict__ xc){
  __shared__ float st[67][CONVC];
  __shared__ float swt[CONVC][4];
  __shared__ float sbias[CONVC];
  const int blk = blockIdx.x;
  const int cg = blk & 1, tile = (blk >> 1) & 15, b = blk >> 5;
  const int l0 = tile << 6, ch0 = cg * CONVC;
  const int tid = threadIdx.x;
  for (int i = tid; i < CONVC; i += 256) {
    float4 wv = *(const float4*)(cw + (size_t)(ch0 + i) * 4);
    swt[i][0] = wv.x; swt[i][1] = wv.y; swt[i][2] = wv.z; swt[i][3] = wv.w;
    sbias[i] = cb[ch0 + i];
  }
  for (int i = tid; i < 67 * 48; i += 256) {
    int rr = i / 48, q4 = i % 48;
    int lrow = l0 + rr - 3;
    float4 v = make_float4(0.f, 0.f, 0.f, 0.f);
    if (lrow >= 0) v = *(const float4*)(zx + ((size_t)(b << 10) + lrow) * DPROJ + DI + ch0 + q4 * 4);
    *(float4*)(&st[rr][q4 * 4]) = v;
  }
  __syncthreads();
  for (int i = tid; i < 64 * CONVC; i += 256) {
    int t = i / CONVC, c2 = i % CONVC;
    float acc = sbias[c2] + st[t][c2] * swt[c2][0] + st[t+1][c2] * swt[c2][1]
              + st[t+2][c2] * swt[c2][2] + st[t+3][c2] * swt[c2][3];
    acc = silu_f(acc);
    xc[((size_t)(b << 10) + l0 + t) * CDIM + ch0 + c2] = acc;
  }
}

// ---------------- SSD step 1: dt + within-chunk cumulative log-decay ----------------
__global__ __launch_bounds__(64) void k_dt(const float* __restrict__ zx,
    const float* __restrict__ dtbias, const float* __restrict__ Alog,
    float* __restrict__ dtb, float* __restrict__ lcb, float* __restrict__ Acb){
  const int blk = blockIdx.x;
  const int c = blk & 15, h = (blk >> 4) & 7, b = blk >> 7;
  const int s = threadIdx.x;
  const int l = (c << 6) + s;
  float raw = zx[((size_t)(b << 10) + l) * DPROJ + 640 + h] + dtbias[h];
  float dt = raw > 20.f ? raw : log1pf(expf(raw));
  float la = dt * (-expf(Alog[h]));
  float cum = la;
  for (int off = 1; off < 64; off <<= 1) {
    float v = __shfl_up(cum, off, 64);
    if (s >= off) cum += v;
  }
  size_t o = ((size_t)((b << 3) + h) << 10) + l;
  dtb[o] = dt; lcb[o] = cum;
  if (s == 63) Acb[blk] = expf(cum);
}

// ---------------- SSD step 2: per-chunk state S_c ----------------
__global__ __launch_bounds__(256) void k_cstate(const float* __restrict__ xc,
    const float* __restrict__ dtb, const float* __restrict__ lcb,
    float* __restrict__ Sc){
  __shared__ float sB[64][64];
  __shared__ float sX[64][32];
  __shared__ float scoef[64];
  const int blk = blockIdx.x;
  const int c = blk & 15, h = (blk >> 4) & 7, b = blk >> 7;
  const int tid = threadIdx.x;
  const int l0 = c << 6;
  for (int i = tid; i < 64 * 16; i += 256) {
    int r = i >> 4, q = i & 15;
    float4 v = *(const float4*)(xc + ((size_t)(b << 10) + l0 + r) * CDIM + DI + q * 4);
    *(float4*)(&sB[r][q * 4]) = v;
  }
  for (int i = tid; i < 64 * 8; i += 256) {
    int r = i >> 3, q = i & 7;
    float4 v = *(const float4*)(xc + ((size_t)(b << 10) + l0 + r) * CDIM + (h << 5) + q * 4);
    *(float4*)(&sX[r][q * 4]) = v;
  }
  if (tid < 64) {
    size_t o = ((size_t)((b << 3) + h) << 10) + l0;
    float lcT = lcb[o + 63];
    scoef[tid] = dtb[o + tid] * __expf(lcT - lcb[o + tid]);
  }
  __syncthreads();
  const int p = tid >> 3, n8 = (tid & 7) << 3;
  float S[8] = {0,0,0,0,0,0,0,0};
  for (int s = 0; s < 64; ++s) {
    const float cf = scoef[s] * sX[s][p];
#pragma unroll
    for (int j = 0; j < 8; ++j) S[j] += cf * sB[s][n8 + j];
  }
  float* dst = Sc + ((size_t)blk << 11) + (p << 6) + n8;
  *(float4*)dst       = make_float4(S[0], S[1], S[2], S[3]);
  *(float4*)(dst + 4) = make_float4(S[4], S[5], S[6], S[7]);
}

// ---------------- SSD step 3: inter-chunk scan ----------------
__global__ __launch_bounds__(256) void k_hscan(float* __restrict__ Sc, const float* __restrict__ Acb){
  const int blk = blockIdx.x;
  const int bh = blk >> 3;
  const int e = ((blk & 7) << 8) + threadIdx.x;
  float hs = 0.f;
  const size_t base = ((size_t)bh << 15) + e;
  for (int c = 0; c < 16; ++c) {
    const size_t o = base + ((size_t)c << 11);
    float v = Sc[o];
    Sc[o] = hs;
    hs = Acb[(bh << 4) + c] * hs + v;
  }
}

// ---------------- SSD step 4: within-chunk outputs — full MFMA ----------------
// G = C.B^T (MFMA), W = mask*decay*G (regs), Y = [W | P.C] @ [X^T ; h0] (MFMA K=128)
// grid NB*NH*16 = 2048, 256 threads (4 waves)
__global__ __launch_bounds__(256) void k_chunky(const float* __restrict__ xc,
    const float* __restrict__ h0buf, const float* __restrict__ dtb,
    const float* __restrict__ lcb, const float* __restrict__ Dsk,
    float* __restrict__ ys){
  __shared__ ushort_t sC[64 * 64];    // [t][n] bf16 swz (A of G)
  __shared__ ushort_t sBm[64 * 64];   // [s][n] bf16 swz (B of G)
  __shared__ ushort_t sAW[64 * 128];  // [t][k] bf16 swz: k<64 = W, k>=64 = P_t*C
  __shared__ ushort_t sBX[32 * 128];  // [p][k] bf16 swz: k<64 = X^T, k>=64 = h0
  __shared__ float sXT[32][65];       // fp32 X^T (skip term)
  __shared__ float sdt[64], slc[64];
  const int blk = blockIdx.x;
  const int c = blk & 15, h = (blk >> 4) & 7, b = blk >> 7;
  const int tid = threadIdx.x;
  const int l0 = c << 6;
  char* pC = (char*)sC; char* pB = (char*)sBm; char* pA = (char*)sAW; char* pX = (char*)sBX;
  const size_t obh = ((size_t)((b << 3) + h) << 10) + l0;
  if (tid < 64) { sdt[tid] = dtb[obh + tid]; slc[tid] = lcb[obh + tid]; }
  {
    // thread: row = tid>>2 (token in chunk), q = tid&3 (16-elem quarter)
    const int row = tid >> 2, q = tid & 3;
    const size_t rowb = ((size_t)(b << 10) + l0 + row) * CDIM;
    const float Pt = __expf(lcb[obh + row]);
    const int xs = (row & 7) << 4;
    // B rows -> sBm
    float4 b0 = *(const float4*)(xc + rowb + DI + q * 16);
    float4 b1 = *(const float4*)(xc + rowb + DI + q * 16 + 4);
    float4 b2 = *(const float4*)(xc + rowb + DI + q * 16 + 8);
    float4 b3 = *(const float4*)(xc + rowb + DI + q * 16 + 12);
    *(short8v*)(pB + row * 128 + ((q * 32) ^ xs))      = pack8(b0, b1);
    *(short8v*)(pB + row * 128 + ((q * 32 + 16) ^ xs)) = pack8(b2, b3);
    // C rows -> sC, and P_t*C -> sAW[k>=64]
    float4 c0 = *(const float4*)(xc + rowb + DI + DS + q * 16);
    float4 c1 = *(const float4*)(xc + rowb + DI + DS + q * 16 + 4);
    float4 c2 = *(const float4*)(xc + rowb + DI + DS + q * 16 + 8);
    float4 c3 = *(const float4*)(xc + rowb + DI + DS + q * 16 + 12);
    *(short8v*)(pC + row * 128 + ((q * 32) ^ xs))      = pack8(c0, c1);
    *(short8v*)(pC + row * 128 + ((q * 32 + 16) ^ xs)) = pack8(c2, c3);
    float4 p0 = make_float4(c0.x*Pt, c0.y*Pt, c0.z*Pt, c0.w*Pt);
    float4 p1 = make_float4(c1.x*Pt, c1.y*Pt, c1.z*Pt, c1.w*Pt);
    float4 p2 = make_float4(c2.x*Pt, c2.y*Pt, c2.z*Pt, c2.w*Pt);
    float4 p3 = make_float4(c3.x*Pt, c3.y*Pt, c3.z*Pt, c3.w*Pt);
    *(short8v*)(pA + row * 256 + ((128 + q * 32) ^ xs))      = pack8(p0, p1);
    *(short8v*)(pA + row * 256 + ((128 + q * 32 + 16) ^ xs)) = pack8(p2, p3);
    // X rows -> sXT (fp32 transpose)
    float4 x0 = *(const float4*)(xc + rowb + (h << 5) + q * 8);
    float4 x1 = *(const float4*)(xc + rowb + (h << 5) + q * 8 + 4);
    sXT[q*8+0][row] = x0.x; sXT[q*8+1][row] = x0.y; sXT[q*8+2][row] = x0.z; sXT[q*8+3][row] = x0.w;
    sXT[q*8+4][row] = x1.x; sXT[q*8+5][row] = x1.y; sXT[q*8+6][row] = x1.z; sXT[q*8+7][row] = x1.w;
  }
  {
    // h0 -> sBX[k>=64]: thread p = tid>>3, n8 = (tid&7)*8
    const int p = tid >> 3, n8 = (tid & 7) << 3;
    float4 h0a = *(const float4*)(h0buf + ((size_t)blk << 11) + (p << 6) + n8);
    float4 h0b = *(const float4*)(h0buf + ((size_t)blk << 11) + (p << 6) + n8 + 4);
    *(short8v*)(pX + p * 256 + (((64 + n8) * 2) ^ ((p & 7) << 4))) = pack8(h0a, h0b);
  }
  __syncthreads();
  {
    // X^T -> bf16 sBX[k<64]
    const int p = tid >> 3, s8 = (tid & 7) << 3;
    short8v vx;
#pragma unroll
    for (int e = 0; e < 8; ++e) vx[e] = (short)f2bf(sXT[p][s8 + e]);
    *(short8v*)(pX + p * 256 + ((s8 * 2) ^ ((p & 7) << 4))) = vx;
  }
  const int w = tid >> 6, l = tid & 63, lr = l & 15, lgp = l >> 4;
  const int xsl = (lr & 7) << 4;
  // ---- G GEMM: D[t][s], wave w owns t-tile w ----
  f32x4 accg[4];
#pragma unroll
  for (int nt = 0; nt < 4; ++nt) accg[nt] = (f32x4){0.f, 0.f, 0.f, 0.f};
  {
    short8v a0 = *(const short8v*)(pC + (16 * w + lr) * 128 + ((lgp * 16) ^ xsl));
    short8v a1 = *(const short8v*)(pC + (16 * w + lr) * 128 + ((64 + lgp * 16) ^ xsl));
#pragma unroll
    for (int nt = 0; nt < 4; ++nt) {
      short8v b0 = *(const short8v*)(pB + (nt * 16 + lr) * 128 + ((lgp * 16) ^ xsl));
      short8v b1 = *(const short8v*)(pB + (nt * 16 + lr) * 128 + ((64 + lgp * 16) ^ xsl));
      accg[nt] = __builtin_amdgcn_mfma_f32_16x16x32_bf16(a0, b0, accg[nt], 0, 0, 0);
      accg[nt] = __builtin_amdgcn_mfma_f32_16x16x32_bf16(a1, b1, accg[nt], 0, 0, 0);
    }
  }
  // ---- mask + decay -> W (bf16) into sAW[k<64] ----
#pragma unroll
  for (int nt = 0; nt < 4; ++nt) {
    const int s = nt * 16 + lr;
    const float ds = sdt[s], ls = slc[s];
#pragma unroll
    for (int r = 0; r < 4; ++r) {
      const int t = 16 * w + lgp * 4 + r;
      float wv = 0.f;
      if (s <= t) wv = ds * __expf(fminf(slc[t] - ls, 0.f)) * accg[nt][r];
      *(ushort_t*)(pA + t * 256 + ((s * 2) ^ ((t & 7) << 4))) = f2bf(wv);
    }
  }
  __syncthreads();
  // ---- Y GEMM: [W | P.C](64x128) @ [X^T ; h0]^T -> Y[t][p], K=128 ----
  f32x4 accy[2];
  accy[0] = (f32x4){0.f, 0.f, 0.f, 0.f};
  accy[1] = (f32x4){0.f, 0.f, 0.f, 0.f};
  short8v aw[4];
#pragma unroll
  for (int ks = 0; ks < 4; ++ks)
    aw[ks] = *(const short8v*)(pA + (16 * w + lr) * 256 + ((ks * 64 + lgp * 16) ^ xsl));
#pragma unroll
  for (int nt = 0; nt < 2; ++nt) {
#pragma unroll
    for (int ks = 0; ks < 4; ++ks) {
      short8v bx = *(const short8v*)(pX + (nt * 16 + lr) * 256 + ((ks * 64 + lgp * 16) ^ xsl));
      accy[nt] = __builtin_amdgcn_mfma_f32_16x16x32_bf16(aw[ks], bx, accy[nt], 0, 0, 0);
    }
  }
  // ---- epilogue: + D_skip * x, store ----
  const float dsk = Dsk[h];
#pragma unroll
  for (int nt = 0; nt < 2; ++nt) {
    const int p = nt * 16 + lr;
#pragma unroll
    for (int r = 0; r < 4; ++r) {
      const int t = 16 * w + lgp * 4 + r;
      ys[((size_t)(b << 10) + l0 + t) * DI + (h << 5) + p] = accy[nt][r] + dsk * sXT[p][t];
    }
  }
}

// ---------------- gate*silu(z), RMSNorm, out_proj (MFMA), residual add ----------------
__global__ __launch_bounds__(256) void k_gateout(const float* __restrict__ zx,
    const float* __restrict__ ys, const ushort_t* __restrict__ owb,
    float* __restrict__ tok){
  __shared__ ushort_t Al[64 * 256];
  __shared__ ushort_t Bl[128 * 64];
  const int m0 = blockIdx.x * 64;
  const int tid = threadIdx.x;
  char* Ab = (char*)Al; char* Bb = (char*)Bl;
  {
    const int r = tid >> 2, t4 = tid & 3;
    const size_t row = (size_t)(m0 + r);
    const float* yp = ys + row * 256 + t4 * 64;
    const float* zp = zx + row * DPROJ + t4 * 64;
    float p[64];
    float sq = 0.f;
#pragma unroll
    for (int k = 0; k < 16; ++k) {
      float4 fy = *(const float4*)(yp + 4 * k);
      float4 fz = *(const float4*)(zp + 4 * k);
      float a0 = fy.x * (fz.x / (1.f + __expf(-fz.x)));
      float a1 = fy.y * (fz.y / (1.f + __expf(-fz.y)));
      float a2 = fy.z * (fz.z / (1.f + __expf(-fz.z)));
      float a3 = fy.w * (fz.w / (1.f + __expf(-fz.w)));
      p[4*k] = a0; p[4*k+1] = a1; p[4*k+2] = a2; p[4*k+3] = a3;
      sq += a0*a0 + a1*a1 + a2*a2 + a3*a3;
    }
    sq += __shfl_xor(sq, 1, 4); sq += __shfl_xor(sq, 2, 4);
    float rstd = rsqrtf(sq * (1.f / 256.f) + EPS);
#pragma unroll
    for (int k = 0; k < 8; ++k) {
      short8v o;
#pragma unroll
      for (int e = 0; e < 8; ++e) o[e] = (short)f2bf(p[8*k + e] * rstd);
      *(short8v*)(Ab + r * 512 + ((t4 * 128 + 16 * k) ^ ((r & 7) << 4))) = o;
    }
  }
  const int w = tid >> 6, l = tid & 63, lr = l & 15, lgp = l >> 4;
  f32x4 acc[8];
#pragma unroll
  for (int nt = 0; nt < 8; ++nt) acc[nt] = (f32x4){0.f, 0.f, 0.f, 0.f};
  for (int kq = 0; kq < 4; ++kq) {
    __syncthreads();
    for (int idx = tid; idx < 128 * 8; idx += 256) {
      int row = idx >> 3, ch = idx & 7;
      short8v v = *(const short8v*)(owb + ((size_t)row << 8) + kq * 64 + (ch << 3));
      *(short8v*)(Bb + row * 128 + ((ch * 16) ^ ((row & 7) << 4))) = v;
    }
    __syncthreads();
    short8v a0 = *(const short8v*)(Ab + (16*w + lr) * 512 + ((kq * 128 +      lgp * 16) ^ ((lr & 7) << 4)));
    short8v a1 = *(const short8v*)(Ab + (16*w + lr) * 512 + ((kq * 128 + 64 + lgp * 16) ^ ((lr & 7) << 4)));
#pragma unroll
    for (int nt = 0; nt < 8; ++nt) {
      short8v b0 = *(const short8v*)(Bb + (nt * 16 + lr) * 128 + ((     lgp * 16) ^ ((lr & 7) << 4)));
      short8v b1 = *(const short8v*)(Bb + (nt * 16 + lr) * 128 + ((64 + lgp * 16) ^ ((lr & 7) << 4)));
      acc[nt] = __builtin_amdgcn_mfma_f32_16x16x32_bf16(a0, b0, acc[nt], 0, 0, 0);
      acc[nt] = __builtin_amdgcn_mfma_f32_16x16x32_bf16(a1, b1, acc[nt], 0, 0, 0);
    }
  }
#pragma unroll
  for (int nt = 0; nt < 8; ++nt) {
#pragma unroll
    for (int r = 0; r < 4; ++r) {
      tok[((size_t)(m0 + 16 * w + lgp * 4 + r)) * 128 + nt * 16 + lr] += acc[nt][r];
    }
  }
}

// ---------------- final LN + attention scores ----------------
__global__ __launch_bounds__(128) void k_score(const float* __restrict__ tok,
    const float* __restrict__ fg, const float* __restrict__ fb,
    const float* __restrict__ w1, const float* __restrict__ b1,
    const float* __restrict__ w2, const float* __restrict__ b2,
    float* __restrict__ tokF, float* __restrict__ sc){
  __shared__ float st[8][128];
  __shared__ float sh[8][64];
  const int blk = blockIdx.x, b = blk >> 7, tg = (blk & 127) << 3, tid = threadIdx.x;
  for (int i = tid; i < 1024; i += 128) {
    int j = i >> 7, d = i & 127;
    st[j][d] = tok[((size_t)(b << 10) + tg + j) * DM + d];
  }
  __syncthreads();
  {
    const int j = tid >> 4, ln = tid & 15;
    float v[8]; float s = 0, sq = 0;
#pragma unroll
    for (int k = 0; k < 8; ++k) { v[k] = st[j][ln + (k << 4)]; s += v[k]; sq += v[k] * v[k]; }
    for (int off = 8; off; off >>= 1) { s += __shfl_xor(s, off, 16); sq += __shfl_xor(sq, off, 16); }
    float mean = s * (1.f / 128.f), var = sq * (1.f / 128.f) - mean * mean;
    float rstd = rsqrtf(var + EPS);
#pragma unroll
    for (int k = 0; k < 8; ++k) {
      int d = ln + (k << 4);
      float o = (v[k] - mean) * rstd * fg[d] + fb[d];
      st[j][d] = o;
      tokF[((size_t)(b << 10) + tg + j) * DM + d] = o;
    }
  }
  __syncthreads();
  {
    const int hh = tid & 63, jh = tid >> 6;
    const float* row = w1 + (size_t)hh * DM;
    const float bb = b1[hh];
    for (int jj = jh; jj < 8; jj += 2) {
      float a = bb;
      for (int d = 0; d < DM; ++d) a += row[d] * st[jj][d];
      sh[jj][hh] = tanhf(a);
    }
  }
  __syncthreads();
  if (tid < 8) {
    float a = b2[0];
    for (int k = 0; k < 64; ++k) a += sh[tid][k] * w2[k];
    sc[(size_t)(b << 10) + tg + tid] = a;
  }
}

// ---------------- softmax pool + l2 normalize ----------------
__global__ __launch_bounds__(256) void k_pool(const float* __restrict__ tokF,
    const float* __restrict__ sc, float* __restrict__ out){
  __shared__ float sw[1024];
  __shared__ float sred[4];
  __shared__ float sp[2][128];
  const int b = blockIdx.x, tid = threadIdx.x, wv = tid >> 6, ln = tid & 63;
  const float* s = sc + ((size_t)b << 10);
  float mx = -1e30f;
  for (int l = tid; l < 1024; l += 256) mx = fmaxf(mx, s[l]);
  for (int off = 32; off; off >>= 1) mx = fmaxf(mx, __shfl_xor(mx, off));
  if (ln == 0) sred[wv] = mx;
  __syncthreads();
  mx = fmaxf(fmaxf(sred[0], sred[1]), fmaxf(sred[2], sred[3]));
  float se = 0;
  for (int l = tid; l < 1024; l += 256) { float e = expf(s[l] - mx); sw[l] = e; se += e; }
  for (int off = 32; off; off >>= 1) se += __shfl_xor(se, off);
  __syncthreads();
  if (ln == 0) sred[wv] = se;
  __syncthreads();
  se = sred[0] + sred[1] + sred[2] + sred[3];
  const float inv = 1.f / se;
  const int d = tid & 127, hf = tid >> 7;
  float acc = 0;
  const float* tf = tokF + ((size_t)b << 10) * DM;
  for (int l = hf * 512; l < (hf + 1) * 512; ++l) acc += sw[l] * tf[(size_t)l * DM + d];
  sp[hf][d] = acc;
  __syncthreads();
  if (tid < 128) sp[0][tid] = (sp[0][tid] + sp[1][tid]) * inv;
  __syncthreads();
  if (tid < 64) {
    float v0 = sp[0][tid], v1 = sp[0][tid + 64];
    float sq = v0 * v0 + v1 * v1;
    for (int off = 32; off; off >>= 1) sq += __shfl_xor(sq, off);
    float nrm = fmaxf(sqrtf(sq), 1e-12f);
    out[(size_t)b * DM + tid]      = v0 / nrm;
    out[(size_t)b * DM + tid + 64] = v1 / nrm;
  }
}

extern "C" void kernel_launch(void* const* d_in, const int* in_sizes, int n_in,
                              void* d_out, int out_size, void* d_ws, size_t ws_size,
                              hipStream_t stream) {
  const float* x       = (const float*)d_in[0];
  const float* patch_w = (const float*)d_in[1];
  const float* patch_b = (const float*)d_in[2];
  const float* pe_g    = (const float*)d_in[3];
  const float* pe_b    = (const float*)d_in[4];
  const float* in_w    = (const float*)d_in[5];
  const float* conv_w  = (const float*)d_in[6];
  const float* conv_b  = (const float*)d_in[7];
  const float* dt_bias = (const float*)d_in[8];
  const float* A_log   = (const float*)d_in[9];
  const float* D_skip  = (const float*)d_in[10];
  const float* nw      = (const float*)d_in[11];
  const float* out_w   = (const float*)d_in[12];
  const float* ln_g    = (const float*)d_in[13];
  const float* ln_b    = (const float*)d_in[14];
  const float* fn_g    = (const float*)d_in[15];
  const float* fn_b    = (const float*)d_in[16];
  const float* w1      = (const float*)d_in[17];
  const float* b1      = (const float*)d_in[18];
  const float* w2      = (const float*)d_in[19];
  const float* b2      = (const float*)d_in[20];
  float* out = (float*)d_out;
  char* ws = (char*)d_ws;

  size_t off = 0;
  float* tok  = (float*)(ws + off); off += (size_t)NB * L * DM * 4;
  float* zx   = (float*)(ws + off); off += (size_t)NB * L * DPROJ * 4;
  float* xcb  = (float*)(ws + off); off += (size_t)NB * L * CDIM * 4;
  float* ysb  = (float*)(ws + off); off += (size_t)NB * L * DI * 4;
  float* Scb  = (float*)(ws + off); off += (size_t)NB * NH * 16 * 2048 * 4;
  float* dtb  = (float*)(ws + off); off += (size_t)NB * NH * L * 4;
  float* lcb  = (float*)(ws + off); off += (size_t)NB * NH * L * 4;
  float* Acb  = (float*)(ws + off); off += (size_t)NB * NH * 16 * 4;
  ushort_t* inwb = (ushort_t*)(ws + off); off += (size_t)4 * EPAD * 128 * 2;
  ushort_t* owb  = (ushort_t*)(ws + off); off += (size_t)4 * 128 * 256 * 2;
  ushort_t* pwb  = (ushort_t*)(ws + off); off += (size_t)128 * 768 * 2;
  float* biasin  = (float*)(ws + off); off += (size_t)4 * EPAD * 4;
  float* tokF = zx;
  float* scb  = (float*)(ws + (size_t)30 * 1024 * 1024);

  {
    const int total = 4 * EPAD * 128 + 4 * 128 * 256 + 128 * 768 + 4 * EPAD;
    k_cvt<<<(total + 255) / 256, 256, 0, stream>>>(in_w, ln_g, ln_b, out_w, nw, patch_w,
                                                   inwb, owb, pwb, biasin);
  }
  k_patch<<<256, 256, 0, stream>>>(x, pwb, patch_b, pe_g, pe_b, tok);
  for (int ly = 0; ly < 4; ++ly) {
    k_inproj<<<1024, 256, 0, stream>>>(tok, inwb + (size_t)ly * EPAD * 128,
                                       biasin + ly * EPAD, zx);
    k_conv<<<NB * 16 * 2, 256, 0, stream>>>(zx, conv_w + (size_t)ly * CDIM * 4,
                                            conv_b + ly * CDIM, xcb);
    k_dt<<<NB * NH * 16, 64, 0, stream>>>(zx, dt_bias + ly * NH, A_log + ly * NH,
                                          dtb, lcb, Acb);
    k_cstate<<<NB * NH * 16, 256, 0, stream>>>(xcb, dtb, lcb, Scb);
    k_hscan<<<NB * NH * 8, 256, 0, stream>>>(Scb, Acb);
    k_chunky<<<NB * NH * 16, 256, 0, stream>>>(xcb, Scb, dtb, lcb,
                                               D_skip + ly * NH, ysb);
    k_gateout<<<256, 256, 0, stream>>>(zx, ysb, owb + (size_t)ly * 128 * 256, tok);
  }
  k_score<<<2048, 128, 0, stream>>>(tok, fn_g, fn_b, w1, b1, w2, b2, tokF, scb);
  k_pool<<<16, 256, 0, stream>>>(tokF, scb, out);
}

// Round 5
// 513.842 us; speedup vs baseline: 5.2959x; 1.1478x over previous
//
#include <hip/hip_runtime.h>
#include <math.h>

#define EPS 1e-5f

constexpr int NB      = 16;
constexpr int L       = 1024;
constexpr int DM      = 128;
constexpr int DI      = 256;
constexpr int DS      = 64;
constexpr int NH      = 8;
constexpr int DPROJ   = 648;   // 2*DI + 2*DS + NH
constexpr int CDIM    = 384;   // DI + 2*DS
constexpr int EPAD    = 656;   // DPROJ padded to 41*16

typedef __attribute__((ext_vector_type(8))) short short8v;
typedef __attribute__((ext_vector_type(4))) float f32x4;
typedef unsigned short ushort_t;

__device__ __forceinline__ float silu_f(float x){ return x / (1.f + expf(-x)); }
__device__ __forceinline__ ushort_t f2bf(float f){
  union { float f; unsigned int u; } v; v.f = f;
  unsigned int r = v.u + 0x7FFF + ((v.u >> 16) & 1);
  return (ushort_t)(r >> 16);
}
__device__ __forceinline__ short8v pack8(float4 a, float4 b){
  short8v v;
  v[0]=(short)f2bf(a.x); v[1]=(short)f2bf(a.y); v[2]=(short)f2bf(a.z); v[3]=(short)f2bf(a.w);
  v[4]=(short)f2bf(b.x); v[5]=(short)f2bf(b.y); v[6]=(short)f2bf(b.z); v[7]=(short)f2bf(b.w);
  return v;
}

// ---------------- weight conversion / folding (runs once per launch) ----------------
__global__ __launch_bounds__(256) void k_cvt(const float* __restrict__ in_w,
    const float* __restrict__ ln_g, const float* __restrict__ ln_b,
    const float* __restrict__ out_w, const float* __restrict__ nw,
    const float* __restrict__ patch_w, const float* __restrict__ w1,
    ushort_t* __restrict__ inwb, ushort_t* __restrict__ owb,
    ushort_t* __restrict__ pwb, float* __restrict__ biasin,
    ushort_t* __restrict__ w1b){
  const int R1 = 4 * EPAD * 128, R2 = 4 * 128 * 256, R3 = 128 * 768, R4 = 4 * EPAD, R5 = 64 * 128;
  int i = blockIdx.x * 256 + threadIdx.x;
  if (i < R1) {
    int ly = i / (EPAD * 128), rem = i % (EPAD * 128), e = rem >> 7, d = rem & 127;
    float v = 0.f;
    if (e < DPROJ) v = in_w[((size_t)ly * DPROJ + e) * 128 + d] * ln_g[ly * 128 + d];
    inwb[i] = f2bf(v);
    return;
  }
  i -= R1;
  if (i < R2) {
    int ly = i >> 15, rem = i & 32767, e = rem & 255;
    owb[i] = f2bf(out_w[i] * nw[ly * 256 + e]);
    return;
  }
  i -= R2;
  if (i < R3) { pwb[i] = f2bf(patch_w[i]); return; }
  i -= R3;
  if (i < R4) {
    int ly = i / EPAD, e = i % EPAD;
    float s = 0.f;
    if (e < DPROJ) {
      const float* r = in_w + ((size_t)ly * DPROJ + e) * 128;
      const float* b = ln_b + ly * 128;
      for (int d = 0; d < 128; ++d) s += r[d] * b[d];
    }
    biasin[i] = s;
    return;
  }
  i -= R4;
  if (i < R5) w1b[i] = f2bf(w1[i]);
}

// ---------------- patch embed (MFMA) + pos layernorm ----------------
__global__ __launch_bounds__(256) void k_patch(const float* __restrict__ x,
    const ushort_t* __restrict__ pwb, const float* __restrict__ pb,
    const float* __restrict__ pg, const float* __restrict__ pbe,
    float* __restrict__ tok){
  __shared__ ushort_t Al[64 * 128];
  __shared__ ushort_t Bl[128 * 128];
  __shared__ float spb[128], spg[128], spe[128];
  const int m0 = blockIdx.x * 64;
  const int tid = threadIdx.x;
  char* Ab = (char*)Al; char* Bb = (char*)Bl;
  if (tid < 128) { spb[tid] = pb[tid]; spg[tid] = pg[tid]; spe[tid] = pbe[tid]; }
  const int w = tid >> 6, l = tid & 63, lr = l & 15, lgp = l >> 4;
  f32x4 acc[8];
#pragma unroll
  for (int nt = 0; nt < 8; ++nt) acc[nt] = (f32x4){0.f, 0.f, 0.f, 0.f};
  for (int kc = 0; kc < 6; ++kc) {
    __syncthreads();
    for (int idx = tid; idx < 128 * 16; idx += 256) {
      int n = idx >> 4, ch = idx & 15;
      short8v v = *(const short8v*)(pwb + (size_t)n * 768 + kc * 128 + (ch << 3));
      *(short8v*)(Bb + n * 256 + ((ch * 16) ^ ((n & 7) << 4))) = v;
    }
    {
      const int c = kc >> 1;
      for (int i = tid; i < 1024; i += 256) {
        int t = i >> 4, p = (i >> 1) & 7, o = i & 1;
        int T = m0 + t, bb = T >> 10, tl = T & 1023, hp = tl >> 5, wp = tl & 31;
        const float* src = x + (((size_t)(bb * 3 + c) * 512 + hp * 16 + ((kc & 1) << 3) + p) * 512
                                + wp * 16 + o * 8);
        float4 f0 = *(const float4*)src;
        float4 f1 = *(const float4*)(src + 4);
        short8v v = pack8(f0, f1);
        int kk = p * 16 + o * 8;
        *(short8v*)(Ab + t * 256 + ((kk * 2) ^ ((t & 7) << 4))) = v;
      }
    }
    __syncthreads();
    short8v a[4];
#pragma unroll
    for (int ks = 0; ks < 4; ++ks)
      a[ks] = *(const short8v*)(Ab + (16 * w + lr) * 256 + ((ks * 64 + lgp * 16) ^ ((lr & 7) << 4)));
#pragma unroll
    for (int nt = 0; nt < 8; ++nt) {
#pragma unroll
      for (int ks = 0; ks < 4; ++ks) {
        short8v b = *(const short8v*)(Bb + (nt * 16 + lr) * 256 + ((ks * 64 + lgp * 16) ^ ((lr & 7) << 4)));
        acc[nt] = __builtin_amdgcn_mfma_f32_16x16x32_bf16(a[ks], b, acc[nt], 0, 0, 0);
      }
    }
  }
  float s4[4] = {0,0,0,0}, q4[4] = {0,0,0,0};
#pragma unroll
  for (int nt = 0; nt < 8; ++nt) {
    const float bb = spb[nt * 16 + lr];
#pragma unroll
    for (int r = 0; r < 4; ++r) { float v = acc[nt][r] + bb; s4[r] += v; q4[r] += v * v; }
  }
#pragma unroll
  for (int r = 0; r < 4; ++r) {
    for (int off = 1; off < 16; off <<= 1) {
      s4[r] += __shfl_xor(s4[r], off, 16);
      q4[r] += __shfl_xor(q4[r], off, 16);
    }
  }
#pragma unroll
  for (int r = 0; r < 4; ++r) {
    float mean = s4[r] * (1.f / 128.f);
    float var  = q4[r] * (1.f / 128.f) - mean * mean;
    float rstd = rsqrtf(var + EPS);
    const size_t row = (size_t)(m0 + 16 * w + lgp * 4 + r) * 128;
#pragma unroll
    for (int nt = 0; nt < 8; ++nt) {
      int col = nt * 16 + lr;
      float v = acc[nt][r] + spb[col];
      tok[row + col] = (v - mean) * rstd * spg[col] + spe[col];
    }
  }
}

// ---------------- fused layernorm + in_proj (MFMA, M=128 tile) ----------------
// grid 512 = 128 m-blocks x 4 n-blocks; 256 threads
__global__ __launch_bounds__(256) void k_inproj(const float* __restrict__ tok,
    const ushort_t* __restrict__ inwb, const float* __restrict__ biasin,
    float* __restrict__ zx){
  __shared__ ushort_t Al[128 * 128];   // 32 KB
  __shared__ ushort_t Bl[176 * 128];   // 45 KB
  __shared__ float sBias[176];
  const int blk = blockIdx.x;
  const int mb = blk >> 2, nb = blk & 3;
  const int m0 = mb << 7, n0 = nb * 176;
  const int NT = (nb == 3) ? 128 : 176;
  const int tid = threadIdx.x;
  char* Ab = (char*)Al; char* Bb = (char*)Bl;
  for (int idx = tid; idx < (NT << 4); idx += 256) {
    int row = idx >> 4, ch = idx & 15;
    short8v v = *(const short8v*)(inwb + ((size_t)(n0 + row) << 7) + (ch << 3));
    *(short8v*)(Bb + row * 256 + ((ch * 16) ^ ((row & 7) << 4))) = v;
  }
  for (int idx = tid; idx < NT; idx += 256) sBias[idx] = biasin[n0 + idx];
  for (int rp = 0; rp < 2; ++rp) {
    const int r = (rp << 6) + (tid >> 2), t4 = tid & 3;
    const float* src = tok + (((size_t)(m0 + r)) << 7) + t4 * 32;
    float v[32];
    float s = 0.f, sq = 0.f;
#pragma unroll
    for (int k = 0; k < 8; ++k) {
      float4 f = *(const float4*)(src + 4 * k);
      v[4*k] = f.x; v[4*k+1] = f.y; v[4*k+2] = f.z; v[4*k+3] = f.w;
      s += f.x + f.y + f.z + f.w;
      sq += f.x*f.x + f.y*f.y + f.z*f.z + f.w*f.w;
    }
    s  += __shfl_xor(s, 1, 4);  s  += __shfl_xor(s, 2, 4);
    sq += __shfl_xor(sq, 1, 4); sq += __shfl_xor(sq, 2, 4);
    float mean = s * (1.f / 128.f);
    float var  = sq * (1.f / 128.f) - mean * mean;
    float rstd = rsqrtf(var + EPS);
#pragma unroll
    for (int k = 0; k < 4; ++k) {
      short8v o;
#pragma unroll
      for (int e = 0; e < 8; ++e) o[e] = (short)f2bf((v[8*k + e] - mean) * rstd);
      *(short8v*)(Ab + r * 256 + ((t4 * 64 + 16 * k) ^ ((r & 7) << 4))) = o;
    }
  }
  __syncthreads();
  const int w = tid >> 6, l = tid & 63, lr = l & 15, lgp = l >> 4;
  const int xsl = (lr & 7) << 4;
  short8v a[2][4];
#pragma unroll
  for (int mi = 0; mi < 2; ++mi) {
    const int mt = w + mi * 4;
#pragma unroll
    for (int ks = 0; ks < 4; ++ks)
      a[mi][ks] = *(const short8v*)(Ab + (16 * mt + lr) * 256 + ((ks * 64 + lgp * 16) ^ xsl));
  }
  const int NTT = NT >> 4;
  for (int nt = 0; nt < NTT; ++nt) {
    f32x4 acc0 = (f32x4){0.f, 0.f, 0.f, 0.f};
    f32x4 acc1 = (f32x4){0.f, 0.f, 0.f, 0.f};
#pragma unroll
    for (int ks = 0; ks < 4; ++ks) {
      short8v b = *(const short8v*)(Bb + (nt * 16 + lr) * 256 + ((ks * 64 + lgp * 16) ^ xsl));
      acc0 = __builtin_amdgcn_mfma_f32_16x16x32_bf16(a[0][ks], b, acc0, 0, 0, 0);
      acc1 = __builtin_amdgcn_mfma_f32_16x16x32_bf16(a[1][ks], b, acc1, 0, 0, 0);
    }
    const int col = n0 + nt * 16 + lr;
    if (col < DPROJ) {
      const float bias = sBias[nt * 16 + lr];
#pragma unroll
      for (int r = 0; r < 4; ++r) {
        zx[((size_t)(m0 + 16 * w       + lgp * 4 + r)) * DPROJ + col] = acc0[r] + bias;
        zx[((size_t)(m0 + 16 * (w + 4) + lgp * 4 + r)) * DPROJ + col] = acc1[r] + bias;
      }
    }
  }
}

// ---------------- causal depthwise conv + silu (LDS-tiled) ----------------
constexpr int CONVC = 192;
__global__ __launch_bounds__(256) void k_conv(const float* __restrict__ zx,
    const float* __restrict__ cw, const float* __restrict__ cb, float* __restrict__ xc){
  __shared__ float st[67][CONVC];
  __shared__ float swt[CONVC][4];
  __shared__ float sbias[CONVC];
  const int blk = blockIdx.x;
  const int cg = blk & 1, tile = (blk >> 1) & 15, b = blk >> 5;
  const int l0 = tile << 6, ch0 = cg * CONVC;
  const int tid = threadIdx.x;
  for (int i = tid; i < CONVC; i += 256) {
    float4 wv = *(const float4*)(cw + (size_t)(ch0 + i) * 4);
    swt[i][0] = wv.x; swt[i][1] = wv.y; swt[i][2] = wv.z; swt[i][3] = wv.w;
    sbias[i] = cb[ch0 + i];
  }
  for (int i = tid; i < 67 * 48; i += 256) {
    int rr = i / 48, q4 = i % 48;
    int lrow = l0 + rr - 3;
    float4 v = make_float4(0.f, 0.f, 0.f, 0.f);
    if (lrow >= 0) v = *(const float4*)(zx + ((size_t)(b << 10) + lrow) * DPROJ + DI + ch0 + q4 * 4);
    *(float4*)(&st[rr][q4 * 4]) = v;
  }
  __syncthreads();
  for (int i = tid; i < 64 * CONVC; i += 256) {
    int t = i / CONVC, c2 = i % CONVC;
    float acc = sbias[c2] + st[t][c2] * swt[c2][0] + st[t+1][c2] * swt[c2][1]
              + st[t+2][c2] * swt[c2][2] + st[t+3][c2] * swt[c2][3];
    acc = silu_f(acc);
    xc[((size_t)(b << 10) + l0 + t) * CDIM + ch0 + c2] = acc;
  }
}

// ---------------- SSD step 1: dt + within-chunk cumulative log-decay ----------------
__global__ __launch_bounds__(64) void k_dt(const float* __restrict__ zx,
    const float* __restrict__ dtbias, const float* __restrict__ Alog,
    float* __restrict__ dtb, float* __restrict__ lcb, float* __restrict__ Acb){
  const int blk = blockIdx.x;
  const int c = blk & 15, h = (blk >> 4) & 7, b = blk >> 7;
  const int s = threadIdx.x;
  const int l = (c << 6) + s;
  float raw = zx[((size_t)(b << 10) + l) * DPROJ + 640 + h] + dtbias[h];
  float dt = raw > 20.f ? raw : log1pf(expf(raw));
  float la = dt * (-expf(Alog[h]));
  float cum = la;
  for (int off = 1; off < 64; off <<= 1) {
    float v = __shfl_up(cum, off, 64);
    if (s >= off) cum += v;
  }
  size_t o = ((size_t)((b << 3) + h) << 10) + l;
  dtb[o] = dt; lcb[o] = cum;
  if (s == 63) Acb[blk] = expf(cum);
}

// ---------------- SSD step 2: per-chunk state S_c (MFMA) ----------------
// S[p][n] = sum_s (coef_s X[s][p]) B[s][n]; A_op[p][s], B_op[n][s] staged transposed bf16
__global__ __launch_bounds__(256) void k_cstate(const float* __restrict__ xc,
    const float* __restrict__ dtb, const float* __restrict__ lcb,
    float* __restrict__ Sc){
  __shared__ ushort_t sXc[32 * 64];   // A_op [p][s]
  __shared__ ushort_t sBt[64 * 64];   // B_op [n][s]
  __shared__ float scoef[64];
  const int blk = blockIdx.x;
  const int c = blk & 15, h = (blk >> 4) & 7, b = blk >> 7;
  const int tid = threadIdx.x;
  const int l0 = c << 6;
  char* pA = (char*)sXc; char* pB = (char*)sBt;
  const size_t obh = ((size_t)((b << 3) + h) << 10) + l0;
  if (tid < 64) {
    float lcT = lcb[obh + 63];
    scoef[tid] = dtb[obh + tid] * __expf(fminf(lcT - lcb[obh + tid], 0.f));
  }
  const int s = tid >> 2, q = tid & 3;
  const size_t rowb = ((size_t)(b << 10) + l0 + s) * CDIM;
  float4 b0 = *(const float4*)(xc + rowb + DI + q * 16);
  float4 b1 = *(const float4*)(xc + rowb + DI + q * 16 + 4);
  float4 b2 = *(const float4*)(xc + rowb + DI + q * 16 + 8);
  float4 b3 = *(const float4*)(xc + rowb + DI + q * 16 + 12);
  float4 x0 = *(const float4*)(xc + rowb + (h << 5) + q * 8);
  float4 x1 = *(const float4*)(xc + rowb + (h << 5) + q * 8 + 4);
  float bv[16] = {b0.x,b0.y,b0.z,b0.w, b1.x,b1.y,b1.z,b1.w,
                  b2.x,b2.y,b2.z,b2.w, b3.x,b3.y,b3.z,b3.w};
#pragma unroll
  for (int j = 0; j < 16; ++j) {
    const int n = q * 16 + j;
    *(ushort_t*)(pB + n * 128 + ((s * 2) ^ ((n & 7) << 4))) = f2bf(bv[j]);
  }
  __syncthreads();
  const float cf = scoef[s];
  float xv[8] = {x0.x,x0.y,x0.z,x0.w, x1.x,x1.y,x1.z,x1.w};
#pragma unroll
  for (int j = 0; j < 8; ++j) {
    const int p = q * 8 + j;
    *(ushort_t*)(pA + p * 128 + ((s * 2) ^ ((p & 7) << 4))) = f2bf(cf * xv[j]);
  }
  __syncthreads();
  const int w = tid >> 6, l = tid & 63, lr = l & 15, lgp = l >> 4;
  const int xsl = (lr & 7) << 4;
  const int pt = w & 1, ng = w >> 1;
  short8v a0 = *(const short8v*)(pA + (pt * 16 + lr) * 128 + ((lgp * 16) ^ xsl));
  short8v a1 = *(const short8v*)(pA + (pt * 16 + lr) * 128 + ((64 + lgp * 16) ^ xsl));
  float* dst = Sc + ((size_t)blk << 11);
#pragma unroll
  for (int ni = 0; ni < 2; ++ni) {
    const int nt = ng * 2 + ni;
    f32x4 acc = (f32x4){0.f, 0.f, 0.f, 0.f};
    short8v bb0 = *(const short8v*)(pB + (nt * 16 + lr) * 128 + ((lgp * 16) ^ xsl));
    short8v bb1 = *(const short8v*)(pB + (nt * 16 + lr) * 128 + ((64 + lgp * 16) ^ xsl));
    acc = __builtin_amdgcn_mfma_f32_16x16x32_bf16(a0, bb0, acc, 0, 0, 0);
    acc = __builtin_amdgcn_mfma_f32_16x16x32_bf16(a1, bb1, acc, 0, 0, 0);
#pragma unroll
    for (int r = 0; r < 4; ++r)
      dst[(pt * 16 + lgp * 4 + r) * 64 + nt * 16 + lr] = acc[r];
  }
}

// ---------------- SSD step 3: inter-chunk scan ----------------
__global__ __launch_bounds__(256) void k_hscan(float* __restrict__ Sc, const float* __restrict__ Acb){
  const int blk = blockIdx.x;
  const int bh = blk >> 3;
  const int e = ((blk & 7) << 8) + threadIdx.x;
  float hs = 0.f;
  const size_t base = ((size_t)bh << 15) + e;
  for (int c = 0; c < 16; ++c) {
    const size_t o = base + ((size_t)c << 11);
    float v = Sc[o];
    Sc[o] = hs;
    hs = Acb[(bh << 4) + c] * hs + v;
  }
}

// ---------------- SSD step 4: within-chunk outputs — full MFMA ----------------
__global__ __launch_bounds__(256) void k_chunky(const float* __restrict__ xc,
    const float* __restrict__ h0buf, const float* __restrict__ dtb,
    const float* __restrict__ lcb, const float* __restrict__ Dsk,
    float* __restrict__ ys){
  __shared__ ushort_t sC[64 * 64];
  __shared__ ushort_t sBm[64 * 64];
  __shared__ ushort_t sAW[64 * 128];
  __shared__ ushort_t sBX[32 * 128];
  __shared__ float sXT[32][65];
  __shared__ float sdt[64], slc[64];
  const int blk = blockIdx.x;
  const int c = blk & 15, h = (blk >> 4) & 7, b = blk >> 7;
  const int tid = threadIdx.x;
  const int l0 = c << 6;
  char* pC = (char*)sC; char* pB = (char*)sBm; char* pA = (char*)sAW; char* pX = (char*)sBX;
  const size_t obh = ((size_t)((b << 3) + h) << 10) + l0;
  if (tid < 64) { sdt[tid] = dtb[obh + tid]; slc[tid] = lcb[obh + tid]; }
  {
    const int row = tid >> 2, q = tid & 3;
    const size_t rowb = ((size_t)(b << 10) + l0 + row) * CDIM;
    const float Pt = __expf(lcb[obh + row]);
    const int xs = (row & 7) << 4;
    float4 b0 = *(const float4*)(xc + rowb + DI + q * 16);
    float4 b1 = *(const float4*)(xc + rowb + DI + q * 16 + 4);
    float4 b2 = *(const float4*)(xc + rowb + DI + q * 16 + 8);
    float4 b3 = *(const float4*)(xc + rowb + DI + q * 16 + 12);
    *(short8v*)(pB + row * 128 + ((q * 32) ^ xs))      = pack8(b0, b1);
    *(short8v*)(pB + row * 128 + ((q * 32 + 16) ^ xs)) = pack8(b2, b3);
    float4 c0 = *(const float4*)(xc + rowb + DI + DS + q * 16);
    float4 c1 = *(const float4*)(xc + rowb + DI + DS + q * 16 + 4);
    float4 c2 = *(const float4*)(xc + rowb + DI + DS + q * 16 + 8);
    float4 c3 = *(const float4*)(xc + rowb + DI + DS + q * 16 + 12);
    *(short8v*)(pC + row * 128 + ((q * 32) ^ xs))      = pack8(c0, c1);
    *(short8v*)(pC + row * 128 + ((q * 32 + 16) ^ xs)) = pack8(c2, c3);
    float4 p0 = make_float4(c0.x*Pt, c0.y*Pt, c0.z*Pt, c0.w*Pt);
    float4 p1 = make_float4(c1.x*Pt, c1.y*Pt, c1.z*Pt, c1.w*Pt);
    float4 p2 = make_float4(c2.x*Pt, c2.y*Pt, c2.z*Pt, c2.w*Pt);
    float4 p3 = make_float4(c3.x*Pt, c3.y*Pt, c3.z*Pt, c3.w*Pt);
    *(short8v*)(pA + row * 256 + ((128 + q * 32) ^ xs))      = pack8(p0, p1);
    *(short8v*)(pA + row * 256 + ((128 + q * 32 + 16) ^ xs)) = pack8(p2, p3);
    float4 x0 = *(const float4*)(xc + rowb + (h << 5) + q * 8);
    float4 x1 = *(const float4*)(xc + rowb + (h << 5) + q * 8 + 4);
    sXT[q*8+0][row] = x0.x; sXT[q*8+1][row] = x0.y; sXT[q*8+2][row] = x0.z; sXT[q*8+3][row] = x0.w;
    sXT[q*8+4][row] = x1.x; sXT[q*8+5][row] = x1.y; sXT[q*8+6][row] = x1.z; sXT[q*8+7][row] = x1.w;
  }
  {
    const int p = tid >> 3, n8 = (tid & 7) << 3;
    float4 h0a = *(const float4*)(h0buf + ((size_t)blk << 11) + (p << 6) + n8);
    float4 h0b = *(const float4*)(h0buf + ((size_t)blk << 11) + (p << 6) + n8 + 4);
    *(short8v*)(pX + p * 256 + (((64 + n8) * 2) ^ ((p & 7) << 4))) = pack8(h0a, h0b);
  }
  __syncthreads();
  {
    const int p = tid >> 3, s8 = (tid & 7) << 3;
    short8v vx;
#pragma unroll
    for (int e = 0; e < 8; ++e) vx[e] = (short)f2bf(sXT[p][s8 + e]);
    *(short8v*)(pX + p * 256 + ((s8 * 2) ^ ((p & 7) << 4))) = vx;
  }
  const int w = tid >> 6, l = tid & 63, lr = l & 15, lgp = l >> 4;
  const int xsl = (lr & 7) << 4;
  f32x4 accg[4];
#pragma unroll
  for (int nt = 0; nt < 4; ++nt) accg[nt] = (f32x4){0.f, 0.f, 0.f, 0.f};
  {
    short8v a0 = *(const short8v*)(pC + (16 * w + lr) * 128 + ((lgp * 16) ^ xsl));
    short8v a1 = *(const short8v*)(pC + (16 * w + lr) * 128 + ((64 + lgp * 16) ^ xsl));
#pragma unroll
    for (int nt = 0; nt < 4; ++nt) {
      short8v b0 = *(const short8v*)(pB + (nt * 16 + lr) * 128 + ((lgp * 16) ^ xsl));
      short8v b1 = *(const short8v*)(pB + (nt * 16 + lr) * 128 + ((64 + lgp * 16) ^ xsl));
      accg[nt] = __builtin_amdgcn_mfma_f32_16x16x32_bf16(a0, b0, accg[nt], 0, 0, 0);
      accg[nt] = __builtin_amdgcn_mfma_f32_16x16x32_bf16(a1, b1, accg[nt], 0, 0, 0);
    }
  }
#pragma unroll
  for (int nt = 0; nt < 4; ++nt) {
    const int s = nt * 16 + lr;
    const float ds = sdt[s], ls = slc[s];
#pragma unroll
    for (int r = 0; r < 4; ++r) {
      const int t = 16 * w + lgp * 4 + r;
      float wv = 0.f;
      if (s <= t) wv = ds * __expf(fminf(slc[t] - ls, 0.f)) * accg[nt][r];
      *(ushort_t*)(pA + t * 256 + ((s * 2) ^ ((t & 7) << 4))) = f2bf(wv);
    }
  }
  __syncthreads();
  f32x4 accy[2];
  accy[0] = (f32x4){0.f, 0.f, 0.f, 0.f};
  accy[1] = (f32x4){0.f, 0.f, 0.f, 0.f};
  short8v aw[4];
#pragma unroll
  for (int ks = 0; ks < 4; ++ks)
    aw[ks] = *(const short8v*)(pA + (16 * w + lr) * 256 + ((ks * 64 + lgp * 16) ^ xsl));
#pragma unroll
  for (int nt = 0; nt < 2; ++nt) {
#pragma unroll
    for (int ks = 0; ks < 4; ++ks) {
      short8v bx = *(const short8v*)(pX + (nt * 16 + lr) * 256 + ((ks * 64 + lgp * 16) ^ xsl));
      accy[nt] = __builtin_amdgcn_mfma_f32_16x16x32_bf16(aw[ks], bx, accy[nt], 0, 0, 0);
    }
  }
  const float dsk = Dsk[h];
#pragma unroll
  for (int nt = 0; nt < 2; ++nt) {
    const int p = nt * 16 + lr;
#pragma unroll
    for (int r = 0; r < 4; ++r) {
      const int t = 16 * w + lgp * 4 + r;
      ys[((size_t)(b << 10) + l0 + t) * DI + (h << 5) + p] = accy[nt][r] + dsk * sXT[p][t];
    }
  }
}

// ---------------- gate*silu(z), RMSNorm, out_proj (MFMA), residual add ----------------
__global__ __launch_bounds__(256) void k_gateout(const float* __restrict__ zx,
    const float* __restrict__ ys, const ushort_t* __restrict__ owb,
    float* __restrict__ tok){
  __shared__ ushort_t Al[64 * 256];
  __shared__ ushort_t Bl[128 * 64];
  const int m0 = blockIdx.x * 64;
  const int tid = threadIdx.x;
  char* Ab = (char*)Al; char* Bb = (char*)Bl;
  {
    const int r = tid >> 2, t4 = tid & 3;
    const size_t row = (size_t)(m0 + r);
    const float* yp = ys + row * 256 + t4 * 64;
    const float* zp = zx + row * DPROJ + t4 * 64;
    float p[64];
    float sq = 0.f;
#pragma unroll
    for (int k = 0; k < 16; ++k) {
      float4 fy = *(const float4*)(yp + 4 * k);
      float4 fz = *(const float4*)(zp + 4 * k);
      float a0 = fy.x * (fz.x / (1.f + __expf(-fz.x)));
      float a1 = fy.y * (fz.y / (1.f + __expf(-fz.y)));
      float a2 = fy.z * (fz.z / (1.f + __expf(-fz.z)));
      float a3 = fy.w * (fz.w / (1.f + __expf(-fz.w)));
      p[4*k] = a0; p[4*k+1] = a1; p[4*k+2] = a2; p[4*k+3] = a3;
      sq += a0*a0 + a1*a1 + a2*a2 + a3*a3;
    }
    sq += __shfl_xor(sq, 1, 4); sq += __shfl_xor(sq, 2, 4);
    float rstd = rsqrtf(sq * (1.f / 256.f) + EPS);
#pragma unroll
    for (int k = 0; k < 8; ++k) {
      short8v o;
#pragma unroll
      for (int e = 0; e < 8; ++e) o[e] = (short)f2bf(p[8*k + e] * rstd);
      *(short8v*)(Ab + r * 512 + ((t4 * 128 + 16 * k) ^ ((r & 7) << 4))) = o;
    }
  }
  const int w = tid >> 6, l = tid & 63, lr = l & 15, lgp = l >> 4;
  f32x4 acc[8];
#pragma unroll
  for (int nt = 0; nt < 8; ++nt) acc[nt] = (f32x4){0.f, 0.f, 0.f, 0.f};
  for (int kq = 0; kq < 4; ++kq) {
    __syncthreads();
    for (int idx = tid; idx < 128 * 8; idx += 256) {
      int row = idx >> 3, ch = idx & 7;
      short8v v = *(const short8v*)(owb + ((size_t)row << 8) + kq * 64 + (ch << 3));
      *(short8v*)(Bb + row * 128 + ((ch * 16) ^ ((row & 7) << 4))) = v;
    }
    __syncthreads();
    short8v a0 = *(const short8v*)(Ab + (16*w + lr) * 512 + ((kq * 128 +      lgp * 16) ^ ((lr & 7) << 4)));
    short8v a1 = *(const short8v*)(Ab + (16*w + lr) * 512 + ((kq * 128 + 64 + lgp * 16) ^ ((lr & 7) << 4)));
#pragma unroll
    for (int nt = 0; nt < 8; ++nt) {
      short8v b0 = *(const short8v*)(Bb + (nt * 16 + lr) * 128 + ((     lgp * 16) ^ ((lr & 7) << 4)));
      short8v b1 = *(const short8v*)(Bb + (nt * 16 + lr) * 128 + ((64 + lgp * 16) ^ ((lr & 7) << 4)));
      acc[nt] = __builtin_amdgcn_mfma_f32_16x16x32_bf16(a0, b0, acc[nt], 0, 0, 0);
      acc[nt] = __builtin_amdgcn_mfma_f32_16x16x32_bf16(a1, b1, acc[nt], 0, 0, 0);
    }
  }
#pragma unroll
  for (int nt = 0; nt < 8; ++nt) {
#pragma unroll
    for (int r = 0; r < 4; ++r) {
      tok[((size_t)(m0 + 16 * w + lgp * 4 + r)) * 128 + nt * 16 + lr] += acc[nt][r];
    }
  }
}

// ---------------- final LN + attention scores (MFMA) ----------------
// grid 256 (64 tokens), 256 threads
__global__ __launch_bounds__(256) void k_score(const float* __restrict__ tok,
    const float* __restrict__ fg, const float* __restrict__ fb,
    const ushort_t* __restrict__ w1b, const float* __restrict__ b1,
    const float* __restrict__ w2, const float* __restrict__ b2,
    float* __restrict__ tokF, float* __restrict__ sc){
  __shared__ ushort_t Al[64 * 128];
  __shared__ ushort_t Wl[64 * 128];
  __shared__ float sb1[64], sw2[64];
  const int m0 = blockIdx.x * 64;
  const int tid = threadIdx.x;
  char* Ab = (char*)Al; char* Wb = (char*)Wl;
  for (int idx = tid; idx < 64 * 16; idx += 256) {
    int row = idx >> 4, ch = idx & 15;
    short8v v = *(const short8v*)(w1b + (row << 7) + (ch << 3));
    *(short8v*)(Wb + row * 256 + ((ch * 16) ^ ((row & 7) << 4))) = v;
  }
  if (tid < 64) { sb1[tid] = b1[tid]; sw2[tid] = w2[tid]; }
  {
    const int r = tid >> 2, t4 = tid & 3;
    const float* src = tok + (((size_t)(m0 + r)) << 7) + t4 * 32;
    float v[32];
    float s = 0.f, sq = 0.f;
#pragma unroll
    for (int k = 0; k < 8; ++k) {
      float4 f = *(const float4*)(src + 4 * k);
      v[4*k] = f.x; v[4*k+1] = f.y; v[4*k+2] = f.z; v[4*k+3] = f.w;
      s += f.x + f.y + f.z + f.w;
      sq += f.x*f.x + f.y*f.y + f.z*f.z + f.w*f.w;
    }
    s  += __shfl_xor(s, 1, 4);  s  += __shfl_xor(s, 2, 4);
    sq += __shfl_xor(sq, 1, 4); sq += __shfl_xor(sq, 2, 4);
    float mean = s * (1.f / 128.f);
    float var  = sq * (1.f / 128.f) - mean * mean;
    float rstd = rsqrtf(var + EPS);
    float* tdst = tokF + (((size_t)(m0 + r)) << 7) + t4 * 32;
#pragma unroll
    for (int k = 0; k < 4; ++k) {
      float o8[8];
      float4 g0 = *(const float4*)(fg + t4 * 32 + 8 * k);
      float4 g1 = *(const float4*)(fg + t4 * 32 + 8 * k + 4);
      float4 e0 = *(const float4*)(fb + t4 * 32 + 8 * k);
      float4 e1 = *(const float4*)(fb + t4 * 32 + 8 * k + 4);
      o8[0] = (v[8*k+0]-mean)*rstd*g0.x + e0.x; o8[1] = (v[8*k+1]-mean)*rstd*g0.y + e0.y;
      o8[2] = (v[8*k+2]-mean)*rstd*g0.z + e0.z; o8[3] = (v[8*k+3]-mean)*rstd*g0.w + e0.w;
      o8[4] = (v[8*k+4]-mean)*rstd*g1.x + e1.x; o8[5] = (v[8*k+5]-mean)*rstd*g1.y + e1.y;
      o8[6] = (v[8*k+6]-mean)*rstd*g1.z + e1.z; o8[7] = (v[8*k+7]-mean)*rstd*g1.w + e1.w;
      *(float4*)(tdst + 8*k)     = make_float4(o8[0], o8[1], o8[2], o8[3]);
      *(float4*)(tdst + 8*k + 4) = make_float4(o8[4], o8[5], o8[6], o8[7]);
      short8v ov;
#pragma unroll
      for (int e = 0; e < 8; ++e) ov[e] = (short)f2bf(o8[e]);
      *(short8v*)(Ab + r * 256 + ((t4 * 64 + 16 * k) ^ ((r & 7) << 4))) = ov;
    }
  }
  __syncthreads();
  const int w = tid >> 6, l = tid & 63, lr = l & 15, lgp = l >> 4;
  const int xsl = (lr & 7) << 4;
  short8v a[4];
#pragma unroll
  for (int ks = 0; ks < 4; ++ks)
    a[ks] = *(const short8v*)(Ab + (16 * w + lr) * 256 + ((ks * 64 + lgp * 16) ^ xsl));
  float sacc[4] = {0.f, 0.f, 0.f, 0.f};
#pragma unroll
  for (int nt = 0; nt < 4; ++nt) {
    f32x4 acc = (f32x4){0.f, 0.f, 0.f, 0.f};
#pragma unroll
    for (int ks = 0; ks < 4; ++ks) {
      short8v bb = *(const short8v*)(Wb + (nt * 16 + lr) * 256 + ((ks * 64 + lgp * 16) ^ xsl));
      acc = __builtin_amdgcn_mfma_f32_16x16x32_bf16(a[ks], bb, acc, 0, 0, 0);
    }
    const float bias = sb1[nt * 16 + lr], wv = sw2[nt * 16 + lr];
#pragma unroll
    for (int r = 0; r < 4; ++r) sacc[r] += tanhf(acc[r] + bias) * wv;
  }
#pragma unroll
  for (int r = 0; r < 4; ++r) {
    for (int off = 1; off < 16; off <<= 1) sacc[r] += __shfl_xor(sacc[r], off, 16);
  }
  if (lr == 0) {
    const float bb2 = b2[0];
#pragma unroll
    for (int r = 0; r < 4; ++r) sc[m0 + 16 * w + lgp * 4 + r] = sacc[r] + bb2;
  }
}

// ---------------- softmax pool phase 1: per-segment partials ----------------
// grid 128 = 16 b x 8 seg; 256 threads
__global__ __launch_bounds__(256) void k_pool1(const float* __restrict__ tokF,
    const float* __restrict__ sc, float* __restrict__ pp){
  __shared__ float sw[128];
  __shared__ float sacc[128];
  __shared__ float sse[2];
  const int bs = blockIdx.x, b = bs >> 3, seg = bs & 7, tid = threadIdx.x;
  const int l0 = (b << 10) + (seg << 7);
  if (tid < 128) sw[tid] = __expf(sc[l0 + tid]);
  __syncthreads();
  const int d = tid & 127, g = tid >> 7;
  const float* tf = tokF + ((size_t)(l0 + (g << 6))) * 128 + d;
  float acc = 0.f;
#pragma unroll 4
  for (int i = 0; i < 64; ++i) acc += sw[(g << 6) + i] * tf[(size_t)i * 128];
  if (g == 0) sacc[d] = acc;
  float e = (tid < 128) ? sw[tid] : 0.f;
  for (int off = 32; off; off >>= 1) e += __shfl_xor(e, off);
  if ((tid & 63) == 0 && tid < 128) sse[tid >> 6] = e;
  __syncthreads();
  if (g == 1) pp[bs * 132 + d] = sacc[d] + acc;
  if (tid == 0) pp[bs * 132 + 128] = sse[0] + sse[1];
}

// ---------------- softmax pool phase 2: reduce + l2 normalize ----------------
// grid 16, 128 threads
__global__ __launch_bounds__(128) void k_pool2(const float* __restrict__ pp,
    float* __restrict__ out){
  __shared__ float s2[2];
  const int b = blockIdx.x, tid = threadIdx.x;
  float num = 0.f, den = 0.f;
#pragma unroll
  for (int seg = 0; seg < 8; ++seg) {
    num += pp[(b * 8 + seg) * 132 + tid];
    den += pp[(b * 8 + seg) * 132 + 128];
  }
  float pooled = num / den;
  float sq = pooled * pooled;
  for (int off = 32; off; off >>= 1) sq += __shfl_xor(sq, off);
  if ((tid & 63) == 0) s2[tid >> 6] = sq;
  __syncthreads();
  float nrm = fmaxf(sqrtf(s2[0] + s2[1]), 1e-12f);
  out[(size_t)b * 128 + tid] = pooled / nrm;
}

extern "C" void kernel_launch(void* const* d_in, const int* in_sizes, int n_in,
                              void* d_out, int out_size, void* d_ws, size_t ws_size,
                              hipStream_t stream) {
  const float* x       = (const float*)d_in[0];
  const float* patch_w = (const float*)d_in[1];
  const float* patch_b = (const float*)d_in[2];
  const float* pe_g    = (const float*)d_in[3];
  const float* pe_b    = (const float*)d_in[4];
  const float* in_w    = (const float*)d_in[5];
  const float* conv_w  = (const float*)d_in[6];
  const float* conv_b  = (const float*)d_in[7];
  const float* dt_bias = (const float*)d_in[8];
  const float* A_log   = (const float*)d_in[9];
  const float* D_skip  = (const float*)d_in[10];
  const float* nw      = (const float*)d_in[11];
  const float* out_w   = (const float*)d_in[12];
  const float* ln_g    = (const float*)d_in[13];
  const float* ln_b    = (const float*)d_in[14];
  const float* fn_g    = (const float*)d_in[15];
  const float* fn_b    = (const float*)d_in[16];
  const float* w1      = (const float*)d_in[17];
  const float* b1      = (const float*)d_in[18];
  const float* w2      = (const float*)d_in[19];
  const float* b2      = (const float*)d_in[20];
  float* out = (float*)d_out;
  char* ws = (char*)d_ws;

  size_t off = 0;
  float* tok  = (float*)(ws + off); off += (size_t)NB * L * DM * 4;
  float* zx   = (float*)(ws + off); off += (size_t)NB * L * DPROJ * 4;
  float* xcb  = (float*)(ws + off); off += (size_t)NB * L * CDIM * 4;
  float* ysb  = (float*)(ws + off); off += (size_t)NB * L * DI * 4;
  float* Scb  = (float*)(ws + off); off += (size_t)NB * NH * 16 * 2048 * 4;
  float* dtb  = (float*)(ws + off); off += (size_t)NB * NH * L * 4;
  float* lcb  = (float*)(ws + off); off += (size_t)NB * NH * L * 4;
  float* Acb  = (float*)(ws + off); off += (size_t)NB * NH * 16 * 4;
  ushort_t* inwb = (ushort_t*)(ws + off); off += (size_t)4 * EPAD * 128 * 2;
  ushort_t* owb  = (ushort_t*)(ws + off); off += (size_t)4 * 128 * 256 * 2;
  ushort_t* pwb  = (ushort_t*)(ws + off); off += (size_t)128 * 768 * 2;
  float* biasin  = (float*)(ws + off); off += (size_t)4 * EPAD * 4;
  ushort_t* w1b  = (ushort_t*)(ws + off); off += (size_t)64 * 128 * 2;
  float* pp      = (float*)(ws + off); off += (size_t)128 * 132 * 4;
  float* tokF = zx;
  float* scb  = (float*)(ws + (size_t)30 * 1024 * 1024);

  {
    const int total = 4 * EPAD * 128 + 4 * 128 * 256 + 128 * 768 + 4 * EPAD + 64 * 128;
    k_cvt<<<(total + 255) / 256, 256, 0, stream>>>(in_w, ln_g, ln_b, out_w, nw, patch_w, w1,
                                                   inwb, owb, pwb, biasin, w1b);
  }
  k_patch<<<256, 256, 0, stream>>>(x, pwb, patch_b, pe_g, pe_b, tok);
  for (int ly = 0; ly < 4; ++ly) {
    k_inproj<<<512, 256, 0, stream>>>(tok, inwb + (size_t)ly * EPAD * 128,
                                      biasin + ly * EPAD, zx);
    k_conv<<<NB * 16 * 2, 256, 0, stream>>>(zx, conv_w + (size_t)ly * CDIM * 4,
                                            conv_b + ly * CDIM, xcb);
    k_dt<<<NB * NH * 16, 64, 0, stream>>>(zx, dt_bias + ly * NH, A_log + ly * NH,
                                          dtb, lcb, Acb);
    k_cstate<<<NB * NH * 16, 256, 0, stream>>>(xcb, dtb, lcb, Scb);
    k_hscan<<<NB * NH * 8, 256, 0, stream>>>(Scb, Acb);
    k_chunky<<<NB * NH * 16, 256, 0, stream>>>(xcb, Scb, dtb, lcb,
                                               D_skip + ly * NH, ysb);
    k_gateout<<<256, 256, 0, stream>>>(zx, ysb, owb + (size_t)ly * 128 * 256, tok);
  }
  k_score<<<256, 256, 0, stream>>>(tok, fn_g, fn_b, w1b, b1, w2, b2, tokF, scb);
  k_pool1<<<128, 256, 0, stream>>>(tokF, scb, pp);
  k_pool2<<<16, 128, 0, stream>>>(pp, out);
}